// Round 1
// baseline (611.722 us; speedup 1.0000x reference)
//
#include <hip/hip_runtime.h>
#include <hip/hip_bf16.h>

#define N_NODES 50000
#define N_EDGES 800000
#define ET_EDGES (N_EDGES + N_NODES)   // 850000
#define NFEAT 128
#define NCLASS 64
#define NHEADS 8
#define HIDDEN 32
#define NOUT (2*HIDDEN + NHEADS*NCLASS)  // 576 = a(32) | b(32) | P(8*64)
#define ROWF NOUT

// ---------------- pack W = [w1_top | w1_bot | proj_w permuted] : [128][576] ----------------
__global__ void k_pack_w(const float* __restrict__ w1, const float* __restrict__ proj_w,
                         float* __restrict__ Wp) {
    int idx = blockIdx.x * 256 + threadIdx.x;
    if (idx >= NFEAT * NOUT) return;
    int k = idx / NOUT, o = idx % NOUT;
    float v;
    if (o < HIDDEN)            v = w1[k * HIDDEN + o];
    else if (o < 2 * HIDDEN)   v = w1[(NFEAT + k) * HIDDEN + (o - HIDDEN)];
    else { int j = o - 2 * HIDDEN; int h = j >> 6; int c = j & 63;
           v = proj_w[(h * NFEAT + k) * NCLASS + c]; }
    Wp[idx] = v;
}

// ---------------- node GEMM: nodebuf[N,576] = x[N,128] @ Wp[128,576] (fp32) ----------------
#define BM 128
#define BN 128
#define BK 32
__global__ __launch_bounds__(256) void k_gemm(const float* __restrict__ x,
                                              const float* __restrict__ Wp,
                                              float* __restrict__ nodebuf) {
    __shared__ __align__(16) float As[BK][BM + 4];  // [k][m], stride 132 floats
    __shared__ __align__(16) float Bs[BK][BN];      // [k][o]
    int tid = threadIdx.x;
    int m0 = blockIdx.x * BM;
    int o0 = blockIdx.y * BN;
    int tm = (tid >> 4) << 3;   // 0..120
    int to = (tid & 15) << 3;   // 0..120
    float acc[8][8];
#pragma unroll
    for (int i = 0; i < 8; ++i)
#pragma unroll
        for (int j = 0; j < 8; ++j) acc[i][j] = 0.f;

    for (int kb = 0; kb < NFEAT; kb += BK) {
        // load A tile (transposed into LDS): x rows coalesced
#pragma unroll
        for (int pass = 0; pass < 4; ++pass) {
            int r  = (tid >> 3) + pass * 32;      // 0..127
            int kk = (tid & 7) * 4;               // 0..28
            int gm = m0 + r;
            float4 v = make_float4(0.f, 0.f, 0.f, 0.f);
            if (gm < N_NODES) v = *(const float4*)(x + (size_t)gm * NFEAT + kb + kk);
            As[kk + 0][r] = v.x; As[kk + 1][r] = v.y;
            As[kk + 2][r] = v.z; As[kk + 3][r] = v.w;
        }
        // load B tile
#pragma unroll
        for (int pass = 0; pass < 4; ++pass) {
            int idx = tid + pass * 256;           // 0..1023 float4s
            int k  = idx >> 5;                    // 0..31
            int o  = (idx & 31) * 4;              // 0..124
            float4 v = make_float4(0.f, 0.f, 0.f, 0.f);
            if (o0 + o < NOUT) v = *(const float4*)(Wp + (size_t)(kb + k) * NOUT + o0 + o);
            *(float4*)&Bs[k][o] = v;
        }
        __syncthreads();
#pragma unroll
        for (int kk = 0; kk < BK; ++kk) {
            float a[8], b[8];
            *(float4*)&a[0] = *(const float4*)&As[kk][tm];
            *(float4*)&a[4] = *(const float4*)&As[kk][tm + 4];
            *(float4*)&b[0] = *(const float4*)&Bs[kk][to];
            *(float4*)&b[4] = *(const float4*)&Bs[kk][to + 4];
#pragma unroll
            for (int i = 0; i < 8; ++i)
#pragma unroll
                for (int j = 0; j < 8; ++j) acc[i][j] = fmaf(a[i], b[j], acc[i][j]);
        }
        __syncthreads();
    }
    int go = o0 + to;
    if (go < NOUT) {
#pragma unroll
        for (int i = 0; i < 8; ++i) {
            int gm = m0 + tm + i;
            if (gm >= N_NODES) break;
            float* dst = nodebuf + (size_t)gm * ROWF + go;
            *(float4*)dst       = make_float4(acc[i][0], acc[i][1], acc[i][2], acc[i][3]);
            *(float4*)(dst + 4) = make_float4(acc[i][4], acc[i][5], acc[i][6], acc[i][7]);
        }
    }
}

// ---------------- per-edge MLP + gate + exp; histogram; partial softmax denom ----------------
__global__ __launch_bounds__(256) void k_edges(const float* __restrict__ nodebuf,
                                               const int* __restrict__ ei,
                                               const float* __restrict__ eww,
                                               const float* __restrict__ b1v,
                                               const float* __restrict__ w2,
                                               const float* __restrict__ b2v,
                                               float* __restrict__ pbuf,
                                               float* __restrict__ denom,
                                               int* __restrict__ deg) {
    int e = blockIdx.x * 256 + threadIdx.x;
    bool valid = e < ET_EDGES;
    int s = 0, d = 0;
    if (valid) {
        if (e < N_EDGES) { s = ei[e]; d = ei[N_EDGES + e]; }
        else             { s = d = e - N_EDGES; }
    }
    const float* arow = nodebuf + (size_t)s * ROWF;
    const float* brow = nodebuf + (size_t)d * ROWF + HIDDEN;
    float h[HIDDEN];
#pragma unroll
    for (int j = 0; j < HIDDEN; j += 4) {
        float4 av = valid ? *(const float4*)(arow + j) : make_float4(0.f,0.f,0.f,0.f);
        float4 bv = valid ? *(const float4*)(brow + j) : make_float4(0.f,0.f,0.f,0.f);
        h[j + 0] = fmaxf(av.x + bv.x + b1v[j + 0], 0.f);
        h[j + 1] = fmaxf(av.y + bv.y + b1v[j + 1], 0.f);
        h[j + 2] = fmaxf(av.z + bv.z + b1v[j + 2], 0.f);
        h[j + 3] = fmaxf(av.w + bv.w + b1v[j + 3], 0.f);
    }
    float z[NHEADS];
#pragma unroll
    for (int t = 0; t < NHEADS; ++t) z[t] = b2v[t];
#pragma unroll
    for (int j = 0; j < HIDDEN; ++j)
#pragma unroll
        for (int t = 0; t < NHEADS; ++t) z[t] = fmaf(h[j], w2[j * NHEADS + t], z[t]);

    float pe[NHEADS];
#pragma unroll
    for (int t = 0; t < NHEADS; ++t) {
        float dyn = 1.f / (1.f + __expf(-z[t]));
        float tw  = valid ? eww[(size_t)t * ET_EDGES + e] * dyn : 0.f;
        tw = tw > 0.f ? tw : 0.01f * tw;                 // leaky_relu
        pe[t] = valid ? __expf(tw) : 0.f;                // softmax numerator (max shift not needed: t<=1.5)
    }
    if (valid) {
        float* pr = pbuf + (size_t)e * 8;
        *(float4*)pr       = make_float4(pe[0], pe[1], pe[2], pe[3]);
        *(float4*)(pr + 4) = make_float4(pe[4], pe[5], pe[6], pe[7]);
        atomicAdd(&deg[d], 1);
    }
    // block-level denom partials
    __shared__ float blk[NHEADS];
    if (threadIdx.x < NHEADS) blk[threadIdx.x] = 0.f;
    __syncthreads();
    int lane = threadIdx.x & 63;
#pragma unroll
    for (int t = 0; t < NHEADS; ++t) {
        float v = pe[t];
        for (int off = 32; off > 0; off >>= 1) v += __shfl_xor(v, off);
        if (lane == 0) atomicAdd(&blk[t], v);
    }
    __syncthreads();
    if (threadIdx.x < NHEADS) atomicAdd(&denom[threadIdx.x], blk[threadIdx.x]);
}

// ---------------- exclusive scan of degrees -> rowptr, cursor (single block) ----------------
__global__ __launch_bounds__(1024) void k_scan(const int* __restrict__ deg,
                                               int* __restrict__ rowptr,
                                               int* __restrict__ cursor) {
    __shared__ int sd[1024];
    int tid = threadIdx.x;
    int run = 0;
    for (int base = 0; base < N_NODES; base += 1024) {
        int i = base + tid;
        int v = (i < N_NODES) ? deg[i] : 0;
        sd[tid] = v;
        __syncthreads();
        for (int off = 1; off < 1024; off <<= 1) {
            int t = (tid >= off) ? sd[tid - off] : 0;
            __syncthreads();
            sd[tid] += t;
            __syncthreads();
        }
        int excl = sd[tid] - v;
        if (i < N_NODES) { rowptr[i] = run + excl; cursor[i] = run + excl; }
        int tot = sd[1023];
        __syncthreads();
        run += tot;
    }
    if (tid == 0) rowptr[N_NODES] = run;
}

// ---------------- scatter edge ids into CSR order ----------------
__global__ void k_scatter(const int* __restrict__ ei, int* __restrict__ cursor,
                          int* __restrict__ eidx) {
    int e = blockIdx.x * 256 + threadIdx.x;
    if (e >= ET_EDGES) return;
    int d = (e < N_EDGES) ? ei[N_EDGES + e] : e - N_EDGES;
    int pos = atomicAdd(&cursor[d], 1);
    eidx[pos] = e;
}

// ---------------- aggregate (wave per node, lane = class) + projection bias + LayerNorm ----------------
__global__ __launch_bounds__(256) void k_agg(const float* __restrict__ nodebuf,
                                             const float* __restrict__ pbuf,
                                             const float* __restrict__ denom,
                                             const int* __restrict__ rowptr,
                                             const int* __restrict__ eidx,
                                             const int* __restrict__ ei,
                                             const float* __restrict__ proj_b,
                                             const float* __restrict__ ln_g,
                                             const float* __restrict__ ln_b,
                                             float* __restrict__ out) {
    int wv = threadIdx.x >> 6, lane = threadIdx.x & 63;
    int n = blockIdx.x * 4 + wv;
    if (n >= N_NODES) return;
    float inv[NHEADS];
#pragma unroll
    for (int t = 0; t < NHEADS; ++t) inv[t] = 1.0f / denom[t];
    float acc = proj_b[lane];
    int beg = rowptr[n], end = rowptr[n + 1];
    for (int idx = beg; idx < end; ++idx) {
        int e = eidx[idx];
        int s = (e < N_EDGES) ? ei[e] : e - N_EDGES;
        const float* pr = pbuf + (size_t)e * 8;
        float4 p0 = *(const float4*)pr;
        float4 p1 = *(const float4*)(pr + 4);
        const float* P = nodebuf + (size_t)s * ROWF + 2 * HIDDEN;
        acc = fmaf(p0.x * inv[0], P[0 * 64 + lane], acc);
        acc = fmaf(p0.y * inv[1], P[1 * 64 + lane], acc);
        acc = fmaf(p0.z * inv[2], P[2 * 64 + lane], acc);
        acc = fmaf(p0.w * inv[3], P[3 * 64 + lane], acc);
        acc = fmaf(p1.x * inv[4], P[4 * 64 + lane], acc);
        acc = fmaf(p1.y * inv[5], P[5 * 64 + lane], acc);
        acc = fmaf(p1.z * inv[6], P[6 * 64 + lane], acc);
        acc = fmaf(p1.w * inv[7], P[7 * 64 + lane], acc);
    }
    // LayerNorm across the 64 lanes (= 64 classes)
    float ssum = acc;
    for (int off = 32; off > 0; off >>= 1) ssum += __shfl_xor(ssum, off);
    float mu = ssum * (1.f / 64.f);
    float df = acc - mu;
    float vs = df * df;
    for (int off = 32; off > 0; off >>= 1) vs += __shfl_xor(vs, off);
    float var = vs * (1.f / 64.f);
    out[(size_t)n * NCLASS + lane] = df * rsqrtf(var + 1e-5f) * ln_g[lane] + ln_b[lane];
}

extern "C" void kernel_launch(void* const* d_in, const int* in_sizes, int n_in,
                              void* d_out, int out_size, void* d_ws, size_t ws_size,
                              hipStream_t stream) {
    const float* x      = (const float*)d_in[0];
    const int*   ei     = (const int*)  d_in[1];
    const float* eww    = (const float*)d_in[2];
    const float* w1     = (const float*)d_in[3];
    const float* b1v    = (const float*)d_in[4];
    const float* w2     = (const float*)d_in[5];
    const float* b2v    = (const float*)d_in[6];
    const float* proj_w = (const float*)d_in[7];
    const float* proj_b = (const float*)d_in[8];
    const float* ln_g   = (const float*)d_in[9];
    const float* ln_b   = (const float*)d_in[10];
    float* out = (float*)d_out;

    char* ws = (char*)d_ws;
    size_t off = 0;
    auto alloc = [&](size_t bytes) -> void* {
        void* p = ws + off;
        off = (off + bytes + 255) & ~(size_t)255;
        return p;
    };
    float* nodebuf = (float*)alloc((size_t)N_NODES * ROWF * 4);   // 115.2 MB
    float* pbuf    = (float*)alloc((size_t)ET_EDGES * 8 * 4);     //  27.2 MB
    float* Wp      = (float*)alloc((size_t)NFEAT * NOUT * 4);     //   0.3 MB
    float* denom   = (float*)alloc(NHEADS * 4);
    int*   deg     = (int*)  alloc((size_t)N_NODES * 4);
    int*   rowptr  = (int*)  alloc((size_t)(N_NODES + 1) * 4);
    int*   cursor  = (int*)  alloc((size_t)N_NODES * 4);
    int*   eidx    = (int*)  alloc((size_t)ET_EDGES * 4);         //   3.4 MB
    if (off > ws_size) return;  // workspace too small: fail loudly (zero output)

    hipMemsetAsync(deg, 0, (size_t)N_NODES * 4, stream);
    hipMemsetAsync(denom, 0, NHEADS * 4, stream);

    k_pack_w<<<(NFEAT * NOUT + 255) / 256, 256, 0, stream>>>(w1, proj_w, Wp);

    dim3 g1((N_NODES + BM - 1) / BM, (NOUT + BN - 1) / BN);
    k_gemm<<<g1, 256, 0, stream>>>(x, Wp, nodebuf);

    k_edges<<<(ET_EDGES + 255) / 256, 256, 0, stream>>>(nodebuf, ei, eww, b1v, w2, b2v,
                                                        pbuf, denom, deg);
    k_scan<<<1, 1024, 0, stream>>>(deg, rowptr, cursor);
    k_scatter<<<(ET_EDGES + 255) / 256, 256, 0, stream>>>(ei, cursor, eidx);
    k_agg<<<(N_NODES + 3) / 4, 256, 0, stream>>>(nodebuf, pbuf, denom, rowptr, eidx, ei,
                                                 proj_b, ln_g, ln_b, out);
}

// Round 2
// 315.721 us; speedup vs baseline: 1.9375x; 1.9375x over previous
//
#include <hip/hip_runtime.h>
#include <hip/hip_bf16.h>

#define N_NODES 50000
#define N_EDGES 800000
#define ET_EDGES (N_EDGES + N_NODES)   // 850000
#define NFEAT 128
#define NCLASS 64
#define NHEADS 8
#define HIDDEN 32
#define NOUT 576   // a(32) | b(32) | P[class][head] (64*8)
typedef unsigned short u16;
typedef unsigned int u32;

typedef __attribute__((ext_vector_type(8))) short bf16x8;
typedef __attribute__((ext_vector_type(4))) float f32x4;

static __device__ __forceinline__ u16 f2bf(float f) {
    u32 u = __float_as_uint(f);
    return (u16)((u + 0x7fffu + ((u >> 16) & 1u)) >> 16);  // RNE
}
static __device__ __forceinline__ float bfl(u32 u) { return __uint_as_float(u << 16); }
static __device__ __forceinline__ float bfh(u32 u) { return __uint_as_float(u & 0xffff0000u); }

// ---- pack WpT[o][k] (bf16, [576][128]): o<32:a | 32..63:b | 64+: P at o=64+c*8+h ----
__global__ void k_pack_w(const float* __restrict__ w1, const float* __restrict__ proj_w,
                         u16* __restrict__ WpT) {
    int idx = blockIdx.x * 256 + threadIdx.x;
    if (idx >= NOUT * NFEAT) return;
    int o = idx / NFEAT, k = idx % NFEAT;
    float v;
    if (o < HIDDEN)           v = w1[k * HIDDEN + o];
    else if (o < 2 * HIDDEN)  v = w1[(NFEAT + k) * HIDDEN + (o - HIDDEN)];
    else { int j = o - 2 * HIDDEN; int c = j >> 3; int h = j & 7;
           v = proj_w[((size_t)h * NFEAT + k) * NCLASS + c]; }
    WpT[idx] = f2bf(v);
}

// ---- cast x -> bf16 [N][128] ----
__global__ __launch_bounds__(256) void k_cast_x(const float* __restrict__ x, u16* __restrict__ xb) {
    int idx = blockIdx.x * 256 + threadIdx.x;   // 800000 threads, 8 elems each
    const float4* xp = (const float4*)(x + (size_t)idx * 8);
    float4 f0 = xp[0], f1 = xp[1];
    uint4 o;
    o.x = (u32)f2bf(f0.x) | ((u32)f2bf(f0.y) << 16);
    o.y = (u32)f2bf(f0.z) | ((u32)f2bf(f0.w) << 16);
    o.z = (u32)f2bf(f1.x) | ((u32)f2bf(f1.y) << 16);
    o.w = (u32)f2bf(f1.z) | ((u32)f2bf(f1.w) << 16);
    *(uint4*)(xb + (size_t)idx * 8) = o;
}

// ---- GEMM: nodebuf[N][576] bf16 = xb[N][128] @ WpT^T, bf16 MFMA 16x16x32, fp32 accum ----
// block: 256 thr = 4 waves; tile 128 rows x 64 cols; 3 col-tiles per block (grid.y=3)
#define ROWP 136
__global__ __launch_bounds__(256) void k_gemm(const u16* __restrict__ xb,
                                              const u16* __restrict__ WpT,
                                              u16* __restrict__ nb) {
    __shared__ __align__(16) u16 As[128 * ROWP];
    __shared__ __align__(16) u16 Bs[64 * ROWP];
    int tid = threadIdx.x;
    int m0 = blockIdx.x * 128;
    int wv = tid >> 6, l = tid & 63, lr = l & 15, lg = l >> 4;

    // stage A once: 128 rows x 128 k
#pragma unroll
    for (int p = 0; p < 8; ++p) {
        int idx = tid + p * 256;
        int row = idx >> 4, fo = idx & 15;
        int gm = m0 + row;
        uint4 v = make_uint4(0u, 0u, 0u, 0u);
        if (gm < N_NODES) v = *(const uint4*)(xb + (size_t)gm * NFEAT + fo * 8);
        *(uint4*)&As[row * ROWP + fo * 8] = v;
    }
    union FR { uint4 q; bf16x8 v; };
    for (int it = 0; it < 3; ++it) {
        int o0 = (blockIdx.y * 3 + it) * 64;
        __syncthreads();   // A ready / prev tile done reading Bs
#pragma unroll
        for (int p = 0; p < 4; ++p) {
            int idx = tid + p * 256;
            int col = idx >> 4, fo = idx & 15;
            *(uint4*)&Bs[col * ROWP + fo * 8] =
                *(const uint4*)(WpT + (size_t)(o0 + col) * NFEAT + fo * 8);
        }
        __syncthreads();
        f32x4 acc[2][4];
#pragma unroll
        for (int fr = 0; fr < 2; ++fr)
#pragma unroll
            for (int fc = 0; fc < 4; ++fc) acc[fr][fc] = (f32x4){0.f, 0.f, 0.f, 0.f};
#pragma unroll
        for (int ks = 0; ks < 4; ++ks) {
            int k0 = ks * 32;
            FR a0, a1, b0, b1, b2, b3;
            a0.q = *(const uint4*)&As[(wv * 32 + 0  + lr) * ROWP + k0 + 8 * lg];
            a1.q = *(const uint4*)&As[(wv * 32 + 16 + lr) * ROWP + k0 + 8 * lg];
            b0.q = *(const uint4*)&Bs[(0  + lr) * ROWP + k0 + 8 * lg];
            b1.q = *(const uint4*)&Bs[(16 + lr) * ROWP + k0 + 8 * lg];
            b2.q = *(const uint4*)&Bs[(32 + lr) * ROWP + k0 + 8 * lg];
            b3.q = *(const uint4*)&Bs[(48 + lr) * ROWP + k0 + 8 * lg];
            acc[0][0] = __builtin_amdgcn_mfma_f32_16x16x32_bf16(a0.v, b0.v, acc[0][0], 0, 0, 0);
            acc[0][1] = __builtin_amdgcn_mfma_f32_16x16x32_bf16(a0.v, b1.v, acc[0][1], 0, 0, 0);
            acc[0][2] = __builtin_amdgcn_mfma_f32_16x16x32_bf16(a0.v, b2.v, acc[0][2], 0, 0, 0);
            acc[0][3] = __builtin_amdgcn_mfma_f32_16x16x32_bf16(a0.v, b3.v, acc[0][3], 0, 0, 0);
            acc[1][0] = __builtin_amdgcn_mfma_f32_16x16x32_bf16(a1.v, b0.v, acc[1][0], 0, 0, 0);
            acc[1][1] = __builtin_amdgcn_mfma_f32_16x16x32_bf16(a1.v, b1.v, acc[1][1], 0, 0, 0);
            acc[1][2] = __builtin_amdgcn_mfma_f32_16x16x32_bf16(a1.v, b2.v, acc[1][2], 0, 0, 0);
            acc[1][3] = __builtin_amdgcn_mfma_f32_16x16x32_bf16(a1.v, b3.v, acc[1][3], 0, 0, 0);
        }
        // direct epilogue: D[row= wv*32+fr*16+4*lg+r][col= o0+fc*16+lr]  (m89-verified C/D map)
#pragma unroll
        for (int fr = 0; fr < 2; ++fr)
#pragma unroll
            for (int fc = 0; fc < 4; ++fc)
#pragma unroll
                for (int r = 0; r < 4; ++r) {
                    int gm = m0 + wv * 32 + fr * 16 + 4 * lg + r;
                    if (gm < N_NODES)
                        nb[(size_t)gm * NOUT + o0 + fc * 16 + lr] = f2bf(acc[fr][fc][r]);
                }
    }
}

// ---- per-edge MLP + gate + exp; deg histogram; softmax denom partials ----
__global__ __launch_bounds__(256) void k_edges(const u16* __restrict__ nb,
                                               const int* __restrict__ ei,
                                               const float* __restrict__ eww,
                                               const float* __restrict__ b1v,
                                               const float* __restrict__ w2,
                                               const float* __restrict__ b2v,
                                               float* __restrict__ pbuf,
                                               float* __restrict__ denom,
                                               int* __restrict__ deg) {
    int e = blockIdx.x * 256 + threadIdx.x;
    bool valid = e < ET_EDGES;
    int s = 0, d = 0;
    if (valid) {
        if (e < N_EDGES) { s = ei[e]; d = ei[N_EDGES + e]; }
        else             { s = d = e - N_EDGES; }
    }
    const uint4* ap = (const uint4*)(nb + (size_t)s * NOUT);
    const uint4* bp = (const uint4*)(nb + (size_t)d * NOUT + HIDDEN);
    float h[HIDDEN];
#pragma unroll
    for (int q = 0; q < 4; ++q) {
        uint4 ua = ap[q], ub = bp[q];
        h[q*8+0] = fmaxf(bfl(ua.x) + bfl(ub.x) + b1v[q*8+0], 0.f);
        h[q*8+1] = fmaxf(bfh(ua.x) + bfh(ub.x) + b1v[q*8+1], 0.f);
        h[q*8+2] = fmaxf(bfl(ua.y) + bfl(ub.y) + b1v[q*8+2], 0.f);
        h[q*8+3] = fmaxf(bfh(ua.y) + bfh(ub.y) + b1v[q*8+3], 0.f);
        h[q*8+4] = fmaxf(bfl(ua.z) + bfl(ub.z) + b1v[q*8+4], 0.f);
        h[q*8+5] = fmaxf(bfh(ua.z) + bfh(ub.z) + b1v[q*8+5], 0.f);
        h[q*8+6] = fmaxf(bfl(ua.w) + bfl(ub.w) + b1v[q*8+6], 0.f);
        h[q*8+7] = fmaxf(bfh(ua.w) + bfh(ub.w) + b1v[q*8+7], 0.f);
    }
    float z[NHEADS];
#pragma unroll
    for (int t = 0; t < NHEADS; ++t) z[t] = b2v[t];
#pragma unroll
    for (int j = 0; j < HIDDEN; ++j)
#pragma unroll
        for (int t = 0; t < NHEADS; ++t) z[t] = fmaf(h[j], w2[j * NHEADS + t], z[t]);

    float pe[NHEADS];
#pragma unroll
    for (int t = 0; t < NHEADS; ++t) {
        float dyn = 1.f / (1.f + __expf(-z[t]));
        float w   = valid ? eww[(size_t)t * ET_EDGES + e] : 0.f;
        float tw  = w * dyn;
        tw = tw > 0.f ? tw : 0.01f * tw;
        pe[t] = valid ? __expf(tw) : 0.f;
    }
    if (valid) {
        float* pr = pbuf + (size_t)e * 8;
        *(float4*)pr       = make_float4(pe[0], pe[1], pe[2], pe[3]);
        *(float4*)(pr + 4) = make_float4(pe[4], pe[5], pe[6], pe[7]);
        atomicAdd(&deg[d], 1);
    }
    __shared__ float blk[NHEADS];
    if (threadIdx.x < NHEADS) blk[threadIdx.x] = 0.f;
    __syncthreads();
    int lane = threadIdx.x & 63;
#pragma unroll
    for (int t = 0; t < NHEADS; ++t) {
        float v = pe[t];
        for (int off = 32; off > 0; off >>= 1) v += __shfl_xor(v, off);
        if (lane == 0) atomicAdd(&blk[t], v);
    }
    __syncthreads();
    if (threadIdx.x < NHEADS) atomicAdd(&denom[threadIdx.x], blk[threadIdx.x]);
}

// ---- scan (3 kernels) ----
__global__ __launch_bounds__(1024) void k_scan1(const int* __restrict__ deg,
                                                int* __restrict__ rowptr,
                                                int* __restrict__ bsum) {
    __shared__ int sd[1024];
    int tid = threadIdx.x;
    int i = blockIdx.x * 1024 + tid;
    int v = (i < N_NODES) ? deg[i] : 0;
    sd[tid] = v;
    __syncthreads();
    for (int off = 1; off < 1024; off <<= 1) {
        int t = (tid >= off) ? sd[tid - off] : 0;
        __syncthreads();
        sd[tid] += t;
        __syncthreads();
    }
    if (i < N_NODES) rowptr[i] = sd[tid] - v;          // local exclusive
    if (tid == 1023) bsum[blockIdx.x] = sd[1023];
}
#define NBLK_SCAN 49
__global__ __launch_bounds__(64) void k_scan2(const int* __restrict__ bsum,
                                              int* __restrict__ boff,
                                              int* __restrict__ rowptr,
                                              const float* __restrict__ denom,
                                              float* __restrict__ dinv) {
    int l = threadIdx.x;
    int orig = (l < NBLK_SCAN) ? bsum[l] : 0;
    int v = orig;
    for (int off = 1; off < 64; off <<= 1) {
        int t = __shfl_up(v, off);
        if (l >= off) v += t;
    }
    if (l < NBLK_SCAN) boff[l] = v - orig;             // exclusive
    if (l == 63) rowptr[N_NODES] = v;                  // total
    if (l < NHEADS) dinv[l] = 1.0f / denom[l];
}
__global__ __launch_bounds__(256) void k_scan3(int* __restrict__ rowptr,
                                               const int* __restrict__ boff,
                                               int* __restrict__ cursor) {
    int i = blockIdx.x * 256 + threadIdx.x;
    if (i >= N_NODES) return;
    int r = rowptr[i] + boff[i >> 10];
    rowptr[i] = r;
    cursor[i] = r;
}

// ---- scatter edge ids + src into CSR order ----
__global__ __launch_bounds__(256) void k_scatter(const int* __restrict__ ei,
                                                 int* __restrict__ cursor,
                                                 int2* __restrict__ esb) {
    int e = blockIdx.x * 256 + threadIdx.x;
    if (e >= ET_EDGES) return;
    int s, d;
    if (e < N_EDGES) { s = ei[e]; d = ei[N_EDGES + e]; }
    else             { s = d = e - N_EDGES; }
    int pos = atomicAdd(&cursor[d], 1);
    esb[pos] = make_int2(e, s);
}

// ---- aggregate (wave/node, lane=class, one uint4 gather per edge) + LayerNorm ----
__global__ __launch_bounds__(256) void k_agg(const u16* __restrict__ nb,
                                             const float* __restrict__ pbuf,
                                             const float* __restrict__ dinv,
                                             const int* __restrict__ rowptr,
                                             const int2* __restrict__ esb,
                                             const float* __restrict__ proj_b,
                                             const float* __restrict__ ln_g,
                                             const float* __restrict__ ln_b,
                                             float* __restrict__ out) {
    int wv = threadIdx.x >> 6, lane = threadIdx.x & 63;
    int n = blockIdx.x * 4 + wv;
    if (n >= N_NODES) return;
    float di[NHEADS];
#pragma unroll
    for (int t = 0; t < NHEADS; ++t) di[t] = dinv[t];
    float acc = proj_b[lane];
    int beg = rowptr[n], end = rowptr[n + 1];
    for (int idx = beg; idx < end; ++idx) {
        int2 es = esb[idx];
        const float4* pp = (const float4*)(pbuf + (size_t)es.x * 8);
        float4 p0 = pp[0], p1 = pp[1];
        // P row: [class][head] bf16; lane's uint4 = class `lane`, heads 0..7
        uint4 pv = *(const uint4*)(nb + (size_t)es.y * NOUT + 2 * HIDDEN + lane * 8);
        acc = fmaf(p0.x * di[0], bfl(pv.x), acc);
        acc = fmaf(p0.y * di[1], bfh(pv.x), acc);
        acc = fmaf(p0.z * di[2], bfl(pv.y), acc);
        acc = fmaf(p0.w * di[3], bfh(pv.y), acc);
        acc = fmaf(p1.x * di[4], bfl(pv.z), acc);
        acc = fmaf(p1.y * di[5], bfh(pv.z), acc);
        acc = fmaf(p1.z * di[6], bfl(pv.w), acc);
        acc = fmaf(p1.w * di[7], bfh(pv.w), acc);
    }
    float ssum = acc;
    for (int off = 32; off > 0; off >>= 1) ssum += __shfl_xor(ssum, off);
    float mu = ssum * (1.f / 64.f);
    float df = acc - mu;
    float vs = df * df;
    for (int off = 32; off > 0; off >>= 1) vs += __shfl_xor(vs, off);
    float var = vs * (1.f / 64.f);
    out[(size_t)n * NCLASS + lane] = df * rsqrtf(var + 1e-5f) * ln_g[lane] + ln_b[lane];
}

extern "C" void kernel_launch(void* const* d_in, const int* in_sizes, int n_in,
                              void* d_out, int out_size, void* d_ws, size_t ws_size,
                              hipStream_t stream) {
    const float* x      = (const float*)d_in[0];
    const int*   ei     = (const int*)  d_in[1];
    const float* eww    = (const float*)d_in[2];
    const float* w1     = (const float*)d_in[3];
    const float* b1v    = (const float*)d_in[4];
    const float* w2     = (const float*)d_in[5];
    const float* b2v    = (const float*)d_in[6];
    const float* proj_w = (const float*)d_in[7];
    const float* proj_b = (const float*)d_in[8];
    const float* ln_g   = (const float*)d_in[9];
    const float* ln_b   = (const float*)d_in[10];
    float* out = (float*)d_out;

    char* ws = (char*)d_ws;
    size_t off = 0;
    auto alloc = [&](size_t bytes) -> void* {
        void* p = ws + off;
        off = (off + bytes + 255) & ~(size_t)255;
        return p;
    };
    u16*   nb     = (u16*)  alloc((size_t)N_NODES * NOUT * 2);    // 57.6 MB
    u16*   xb     = (u16*)  alloc((size_t)N_NODES * NFEAT * 2);   // 12.8 MB
    u16*   WpT    = (u16*)  alloc((size_t)NOUT * NFEAT * 2);      // 0.15 MB
    float* pbuf   = (float*)alloc((size_t)ET_EDGES * 8 * 4);      // 27.2 MB
    float* denom  = (float*)alloc(NHEADS * 4);
    float* dinv   = (float*)alloc(NHEADS * 4);
    int*   deg    = (int*)  alloc((size_t)N_NODES * 4);
    int*   rowptr = (int*)  alloc((size_t)(N_NODES + 1) * 4);
    int*   cursor = (int*)  alloc((size_t)N_NODES * 4);
    int*   bsum   = (int*)  alloc(64 * 4);
    int*   boff   = (int*)  alloc(64 * 4);
    int2*  esb    = (int2*) alloc((size_t)ET_EDGES * 8);          // 6.8 MB
    if (off > ws_size) return;

    hipMemsetAsync(deg, 0, (size_t)N_NODES * 4, stream);
    hipMemsetAsync(denom, 0, NHEADS * 4, stream);

    k_pack_w<<<(NOUT * NFEAT + 255) / 256, 256, 0, stream>>>(w1, proj_w, WpT);
    k_cast_x<<<(N_NODES * NFEAT / 8 + 255) / 256, 256, 0, stream>>>(x, xb);

    dim3 gg((N_NODES + 127) / 128, 3);
    k_gemm<<<gg, 256, 0, stream>>>(xb, WpT, nb);

    k_edges<<<(ET_EDGES + 255) / 256, 256, 0, stream>>>(nb, ei, eww, b1v, w2, b2v,
                                                        pbuf, denom, deg);
    k_scan1<<<NBLK_SCAN, 1024, 0, stream>>>(deg, rowptr, bsum);
    k_scan2<<<1, 64, 0, stream>>>(bsum, boff, rowptr, denom, dinv);
    k_scan3<<<(N_NODES + 255) / 256, 256, 0, stream>>>(rowptr, boff, cursor);
    k_scatter<<<(ET_EDGES + 255) / 256, 256, 0, stream>>>(ei, cursor, esb);
    k_agg<<<(N_NODES + 3) / 4, 256, 0, stream>>>(nb, pbuf, dinv, rowptr, esb,
                                                 proj_b, ln_g, ln_b, out);
}

// Round 3
// 289.197 us; speedup vs baseline: 2.1152x; 1.0917x over previous
//
#include <hip/hip_runtime.h>
#include <hip/hip_bf16.h>

#define N_NODES 50000
#define N_EDGES 800000
#define ET_EDGES (N_EDGES + N_NODES)   // 850000
#define NFEAT 128
#define NCLASS 64
#define NHEADS 8
#define HIDDEN 32
#define NOUT 576   // a(32) | b(32) | P[class][head] (64*8)
typedef unsigned short u16;
typedef unsigned int u32;

typedef __attribute__((ext_vector_type(8))) short bf16x8;
typedef __attribute__((ext_vector_type(4))) float f32x4;

static __device__ __forceinline__ u16 f2bf(float f) {
    u32 u = __float_as_uint(f);
    return (u16)((u + 0x7fffu + ((u >> 16) & 1u)) >> 16);  // RNE
}
static __device__ __forceinline__ u32 pack2bf(float lo, float hi) {
    return (u32)f2bf(lo) | ((u32)f2bf(hi) << 16);
}
static __device__ __forceinline__ float bfl(u32 u) { return __uint_as_float(u << 16); }
static __device__ __forceinline__ float bfh(u32 u) { return __uint_as_float(u & 0xffff0000u); }

// ---- pack WpT[o][k] (bf16, [576][128]): o<32:a | 32..63:b | 64+: P at o=64+c*8+h ----
__global__ void k_pack_w(const float* __restrict__ w1, const float* __restrict__ proj_w,
                         u16* __restrict__ WpT) {
    int idx = blockIdx.x * 256 + threadIdx.x;
    if (idx >= NOUT * NFEAT) return;
    int o = idx / NFEAT, k = idx % NFEAT;
    float v;
    if (o < HIDDEN)           v = w1[k * HIDDEN + o];
    else if (o < 2 * HIDDEN)  v = w1[(NFEAT + k) * HIDDEN + (o - HIDDEN)];
    else { int j = o - 2 * HIDDEN; int c = j >> 3; int h = j & 7;
           v = proj_w[((size_t)h * NFEAT + k) * NCLASS + c]; }
    WpT[idx] = f2bf(v);
}

// ---- GEMM: nb[N][576] bf16 = x[N][128] @ WpT^T, bf16 MFMA 16x16x32, fp32 accum ----
#define ROWP 136
__global__ __launch_bounds__(256) void k_gemm(const float* __restrict__ x,
                                              const u16* __restrict__ WpT,
                                              u16* __restrict__ nb) {
    __shared__ __align__(16) u16 As[128 * ROWP];
    __shared__ __align__(16) u16 Bs[64 * ROWP];
    int tid = threadIdx.x;
    int m0 = blockIdx.x * 128;
    int wv = tid >> 6, l = tid & 63, lr = l & 15, lg = l >> 4;

    // stage A once: 128 rows x 128 k, fp32 -> bf16 on the fly
#pragma unroll
    for (int p = 0; p < 8; ++p) {
        int idx = tid + p * 256;
        int row = idx >> 4, fo = idx & 15;
        int gm = m0 + row;
        float4 f0 = make_float4(0.f,0.f,0.f,0.f), f1 = f0;
        if (gm < N_NODES) {
            const float* xp = x + (size_t)gm * NFEAT + fo * 8;
            f0 = *(const float4*)xp;
            f1 = *(const float4*)(xp + 4);
        }
        uint4 v;
        v.x = pack2bf(f0.x, f0.y); v.y = pack2bf(f0.z, f0.w);
        v.z = pack2bf(f1.x, f1.y); v.w = pack2bf(f1.z, f1.w);
        *(uint4*)&As[row * ROWP + fo * 8] = v;
    }
    union FR { uint4 q; bf16x8 v; };
    for (int it = 0; it < 3; ++it) {
        int o0 = (blockIdx.y * 3 + it) * 64;
        __syncthreads();   // A ready / prev tile done reading Bs
#pragma unroll
        for (int p = 0; p < 4; ++p) {
            int idx = tid + p * 256;
            int col = idx >> 4, fo = idx & 15;
            *(uint4*)&Bs[col * ROWP + fo * 8] =
                *(const uint4*)(WpT + (size_t)(o0 + col) * NFEAT + fo * 8);
        }
        __syncthreads();
        f32x4 acc[2][4];
#pragma unroll
        for (int fr = 0; fr < 2; ++fr)
#pragma unroll
            for (int fc = 0; fc < 4; ++fc) acc[fr][fc] = (f32x4){0.f, 0.f, 0.f, 0.f};
#pragma unroll
        for (int ks = 0; ks < 4; ++ks) {
            int k0 = ks * 32;
            FR a0, a1, b0, b1, b2, b3;
            a0.q = *(const uint4*)&As[(wv * 32 + 0  + lr) * ROWP + k0 + 8 * lg];
            a1.q = *(const uint4*)&As[(wv * 32 + 16 + lr) * ROWP + k0 + 8 * lg];
            b0.q = *(const uint4*)&Bs[(0  + lr) * ROWP + k0 + 8 * lg];
            b1.q = *(const uint4*)&Bs[(16 + lr) * ROWP + k0 + 8 * lg];
            b2.q = *(const uint4*)&Bs[(32 + lr) * ROWP + k0 + 8 * lg];
            b3.q = *(const uint4*)&Bs[(48 + lr) * ROWP + k0 + 8 * lg];
            acc[0][0] = __builtin_amdgcn_mfma_f32_16x16x32_bf16(a0.v, b0.v, acc[0][0], 0, 0, 0);
            acc[0][1] = __builtin_amdgcn_mfma_f32_16x16x32_bf16(a0.v, b1.v, acc[0][1], 0, 0, 0);
            acc[0][2] = __builtin_amdgcn_mfma_f32_16x16x32_bf16(a0.v, b2.v, acc[0][2], 0, 0, 0);
            acc[0][3] = __builtin_amdgcn_mfma_f32_16x16x32_bf16(a0.v, b3.v, acc[0][3], 0, 0, 0);
            acc[1][0] = __builtin_amdgcn_mfma_f32_16x16x32_bf16(a1.v, b0.v, acc[1][0], 0, 0, 0);
            acc[1][1] = __builtin_amdgcn_mfma_f32_16x16x32_bf16(a1.v, b1.v, acc[1][1], 0, 0, 0);
            acc[1][2] = __builtin_amdgcn_mfma_f32_16x16x32_bf16(a1.v, b2.v, acc[1][2], 0, 0, 0);
            acc[1][3] = __builtin_amdgcn_mfma_f32_16x16x32_bf16(a1.v, b3.v, acc[1][3], 0, 0, 0);
        }
        // D[row= wv*32+fr*16+4*lg+r][col= o0+fc*16+lr]  (m89-verified C/D map)
#pragma unroll
        for (int fr = 0; fr < 2; ++fr)
#pragma unroll
            for (int fc = 0; fc < 4; ++fc)
#pragma unroll
                for (int r = 0; r < 4; ++r) {
                    int gm = m0 + wv * 32 + fr * 16 + 4 * lg + r;
                    if (gm < N_NODES)
                        nb[(size_t)gm * NOUT + o0 + fc * 16 + lr] = f2bf(acc[fr][fc][r]);
                }
    }
}

// ---- per-edge MLP + gate + exp; deg histogram; softmax denom partials ----
__global__ __launch_bounds__(256) void k_edges(const u16* __restrict__ nb,
                                               const int* __restrict__ ei,
                                               const float* __restrict__ eww,
                                               const float* __restrict__ b1v,
                                               const float* __restrict__ w2,
                                               const float* __restrict__ b2v,
                                               float* __restrict__ pbuf,
                                               float* __restrict__ denom,
                                               int* __restrict__ deg) {
    int e = blockIdx.x * 256 + threadIdx.x;
    bool valid = e < ET_EDGES;
    int s = 0, d = 0;
    if (valid) {
        if (e < N_EDGES) { s = ei[e]; d = ei[N_EDGES + e]; }
        else             { s = d = e - N_EDGES; }
    }
    const uint4* ap = (const uint4*)(nb + (size_t)s * NOUT);
    const uint4* bp = (const uint4*)(nb + (size_t)d * NOUT + HIDDEN);
    float h[HIDDEN];
#pragma unroll
    for (int q = 0; q < 4; ++q) {
        uint4 ua = ap[q], ub = bp[q];
        h[q*8+0] = fmaxf(bfl(ua.x) + bfl(ub.x) + b1v[q*8+0], 0.f);
        h[q*8+1] = fmaxf(bfh(ua.x) + bfh(ub.x) + b1v[q*8+1], 0.f);
        h[q*8+2] = fmaxf(bfl(ua.y) + bfl(ub.y) + b1v[q*8+2], 0.f);
        h[q*8+3] = fmaxf(bfh(ua.y) + bfh(ub.y) + b1v[q*8+3], 0.f);
        h[q*8+4] = fmaxf(bfl(ua.z) + bfl(ub.z) + b1v[q*8+4], 0.f);
        h[q*8+5] = fmaxf(bfh(ua.z) + bfh(ub.z) + b1v[q*8+5], 0.f);
        h[q*8+6] = fmaxf(bfl(ua.w) + bfl(ub.w) + b1v[q*8+6], 0.f);
        h[q*8+7] = fmaxf(bfh(ua.w) + bfh(ub.w) + b1v[q*8+7], 0.f);
    }
    float z[NHEADS];
#pragma unroll
    for (int t = 0; t < NHEADS; ++t) z[t] = b2v[t];
#pragma unroll
    for (int j = 0; j < HIDDEN; ++j)
#pragma unroll
        for (int t = 0; t < NHEADS; ++t) z[t] = fmaf(h[j], w2[j * NHEADS + t], z[t]);

    float pe[NHEADS];
#pragma unroll
    for (int t = 0; t < NHEADS; ++t) {
        float dyn = 1.f / (1.f + __expf(-z[t]));
        float w   = valid ? eww[(size_t)t * ET_EDGES + e] : 0.f;
        float tw  = w * dyn;
        tw = tw > 0.f ? tw : 0.01f * tw;
        pe[t] = valid ? __expf(tw) : 0.f;
    }
    if (valid) {
        float* pr = pbuf + (size_t)e * 8;
        *(float4*)pr       = make_float4(pe[0], pe[1], pe[2], pe[3]);
        *(float4*)(pr + 4) = make_float4(pe[4], pe[5], pe[6], pe[7]);
        atomicAdd(&deg[d], 1);
    }
    __shared__ float blk[NHEADS];
    if (threadIdx.x < NHEADS) blk[threadIdx.x] = 0.f;
    __syncthreads();
    int lane = threadIdx.x & 63;
#pragma unroll
    for (int t = 0; t < NHEADS; ++t) {
        float v = pe[t];
        for (int off = 32; off > 0; off >>= 1) v += __shfl_xor(v, off);
        if (lane == 0) atomicAdd(&blk[t], v);
    }
    __syncthreads();
    if (threadIdx.x < NHEADS) atomicAdd(&denom[threadIdx.x], blk[threadIdx.x]);
}

// ---- scan (3 kernels) ----
__global__ __launch_bounds__(1024) void k_scan1(const int* __restrict__ deg,
                                                int* __restrict__ rowptr,
                                                int* __restrict__ bsum) {
    __shared__ int sd[1024];
    int tid = threadIdx.x;
    int i = blockIdx.x * 1024 + tid;
    int v = (i < N_NODES) ? deg[i] : 0;
    sd[tid] = v;
    __syncthreads();
    for (int off = 1; off < 1024; off <<= 1) {
        int t = (tid >= off) ? sd[tid - off] : 0;
        __syncthreads();
        sd[tid] += t;
        __syncthreads();
    }
    if (i < N_NODES) rowptr[i] = sd[tid] - v;          // local exclusive
    if (tid == 1023) bsum[blockIdx.x] = sd[1023];
}
#define NBLK_SCAN 49
__global__ __launch_bounds__(64) void k_scan2(const int* __restrict__ bsum,
                                              int* __restrict__ boff,
                                              int* __restrict__ rowptr,
                                              const float* __restrict__ denom,
                                              float* __restrict__ dinv) {
    int l = threadIdx.x;
    int orig = (l < NBLK_SCAN) ? bsum[l] : 0;
    int v = orig;
    for (int off = 1; off < 64; off <<= 1) {
        int t = __shfl_up(v, off);
        if (l >= off) v += t;
    }
    if (l < NBLK_SCAN) boff[l] = v - orig;             // exclusive
    if (l == 63) rowptr[N_NODES] = v;                  // total
    if (l < NHEADS) dinv[l] = 1.0f / denom[l];
}
__global__ __launch_bounds__(256) void k_scan3(int* __restrict__ rowptr,
                                               const int* __restrict__ boff,
                                               int* __restrict__ cursor) {
    int i = blockIdx.x * 256 + threadIdx.x;
    if (i >= N_NODES) return;
    int r = rowptr[i] + boff[i >> 10];
    rowptr[i] = r;
    cursor[i] = r;
}

// ---- scatter: normalize weights, pack bf16, write CSR-ordered wbuf + srcb ----
__global__ __launch_bounds__(256) void k_scatter(const int* __restrict__ ei,
                                                 const float* __restrict__ pbuf,
                                                 const float* __restrict__ dinv,
                                                 int* __restrict__ cursor,
                                                 u16* __restrict__ wbuf,
                                                 int* __restrict__ srcb) {
    int e = blockIdx.x * 256 + threadIdx.x;
    if (e >= ET_EDGES) return;
    int s, d;
    if (e < N_EDGES) { s = ei[e]; d = ei[N_EDGES + e]; }
    else             { s = d = e - N_EDGES; }
    const float4* pp = (const float4*)(pbuf + (size_t)e * 8);
    float4 p0 = pp[0], p1 = pp[1];
    uint4 w;
    w.x = pack2bf(p0.x * dinv[0], p0.y * dinv[1]);
    w.y = pack2bf(p0.z * dinv[2], p0.w * dinv[3]);
    w.z = pack2bf(p1.x * dinv[4], p1.y * dinv[5]);
    w.w = pack2bf(p1.z * dinv[6], p1.w * dinv[7]);
    int pos = atomicAdd(&cursor[d], 1);
    *(uint4*)(wbuf + (size_t)pos * 8) = w;
    srcb[pos] = s;
}

// ---- aggregate (wave/node, lane=class) + LayerNorm; streams are CSR-coalesced ----
__global__ __launch_bounds__(256) void k_agg(const u16* __restrict__ nb,
                                             const u16* __restrict__ wbuf,
                                             const int* __restrict__ srcb,
                                             const int* __restrict__ rowptr,
                                             const float* __restrict__ proj_b,
                                             const float* __restrict__ ln_g,
                                             const float* __restrict__ ln_b,
                                             float* __restrict__ out) {
    int wv = threadIdx.x >> 6, lane = threadIdx.x & 63;
    int n = blockIdx.x * 4 + wv;
    if (n >= N_NODES) return;
    float acc = proj_b[lane];
    int beg = rowptr[n], end = rowptr[n + 1];
    int idx = beg;
    for (; idx + 2 <= end; idx += 2) {
        int s0 = srcb[idx], s1 = srcb[idx + 1];
        uint4 w0 = *(const uint4*)(wbuf + (size_t)idx * 8);
        uint4 w1 = *(const uint4*)(wbuf + (size_t)(idx + 1) * 8);
        uint4 q0 = *(const uint4*)(nb + (size_t)s0 * NOUT + 2 * HIDDEN + lane * 8);
        uint4 q1 = *(const uint4*)(nb + (size_t)s1 * NOUT + 2 * HIDDEN + lane * 8);
        acc = fmaf(bfl(w0.x), bfl(q0.x), acc);
        acc = fmaf(bfh(w0.x), bfh(q0.x), acc);
        acc = fmaf(bfl(w0.y), bfl(q0.y), acc);
        acc = fmaf(bfh(w0.y), bfh(q0.y), acc);
        acc = fmaf(bfl(w0.z), bfl(q0.z), acc);
        acc = fmaf(bfh(w0.z), bfh(q0.z), acc);
        acc = fmaf(bfl(w0.w), bfl(q0.w), acc);
        acc = fmaf(bfh(w0.w), bfh(q0.w), acc);
        acc = fmaf(bfl(w1.x), bfl(q1.x), acc);
        acc = fmaf(bfh(w1.x), bfh(q1.x), acc);
        acc = fmaf(bfl(w1.y), bfl(q1.y), acc);
        acc = fmaf(bfh(w1.y), bfh(q1.y), acc);
        acc = fmaf(bfl(w1.z), bfl(q1.z), acc);
        acc = fmaf(bfh(w1.z), bfh(q1.z), acc);
        acc = fmaf(bfl(w1.w), bfl(q1.w), acc);
        acc = fmaf(bfh(w1.w), bfh(q1.w), acc);
    }
    if (idx < end) {
        int s0 = srcb[idx];
        uint4 w0 = *(const uint4*)(wbuf + (size_t)idx * 8);
        uint4 q0 = *(const uint4*)(nb + (size_t)s0 * NOUT + 2 * HIDDEN + lane * 8);
        acc = fmaf(bfl(w0.x), bfl(q0.x), acc);
        acc = fmaf(bfh(w0.x), bfh(q0.x), acc);
        acc = fmaf(bfl(w0.y), bfl(q0.y), acc);
        acc = fmaf(bfh(w0.y), bfh(q0.y), acc);
        acc = fmaf(bfl(w0.z), bfl(q0.z), acc);
        acc = fmaf(bfh(w0.z), bfh(q0.z), acc);
        acc = fmaf(bfl(w0.w), bfl(q0.w), acc);
        acc = fmaf(bfh(w0.w), bfh(q0.w), acc);
    }
    float ssum = acc;
    for (int off = 32; off > 0; off >>= 1) ssum += __shfl_xor(ssum, off);
    float mu = ssum * (1.f / 64.f);
    float df = acc - mu;
    float vs = df * df;
    for (int off = 32; off > 0; off >>= 1) vs += __shfl_xor(vs, off);
    float var = vs * (1.f / 64.f);
    out[(size_t)n * NCLASS + lane] = df * rsqrtf(var + 1e-5f) * ln_g[lane] + ln_b[lane];
}

extern "C" void kernel_launch(void* const* d_in, const int* in_sizes, int n_in,
                              void* d_out, int out_size, void* d_ws, size_t ws_size,
                              hipStream_t stream) {
    const float* x      = (const float*)d_in[0];
    const int*   ei     = (const int*)  d_in[1];
    const float* eww    = (const float*)d_in[2];
    const float* w1     = (const float*)d_in[3];
    const float* b1v    = (const float*)d_in[4];
    const float* w2     = (const float*)d_in[5];
    const float* b2v    = (const float*)d_in[6];
    const float* proj_w = (const float*)d_in[7];
    const float* proj_b = (const float*)d_in[8];
    const float* ln_g   = (const float*)d_in[9];
    const float* ln_b   = (const float*)d_in[10];
    float* out = (float*)d_out;

    char* ws = (char*)d_ws;
    size_t off = 0;
    auto alloc = [&](size_t bytes) -> void* {
        void* p = ws + off;
        off = (off + bytes + 255) & ~(size_t)255;
        return p;
    };
    u16*   nb     = (u16*)  alloc((size_t)N_NODES * NOUT * 2);    // 57.6 MB
    u16*   WpT    = (u16*)  alloc((size_t)NOUT * NFEAT * 2);      // 0.15 MB
    float* pbuf   = (float*)alloc((size_t)ET_EDGES * 8 * 4);      // 27.2 MB
    u16*   wbuf   = (u16*)  alloc((size_t)ET_EDGES * 8 * 2);      // 13.6 MB
    int*   srcb   = (int*)  alloc((size_t)ET_EDGES * 4);          //  3.4 MB
    float* denom  = (float*)alloc(NHEADS * 4);
    float* dinv   = (float*)alloc(NHEADS * 4);
    int*   deg    = (int*)  alloc((size_t)N_NODES * 4);
    int*   rowptr = (int*)  alloc((size_t)(N_NODES + 1) * 4);
    int*   cursor = (int*)  alloc((size_t)N_NODES * 4);
    int*   bsum   = (int*)  alloc(64 * 4);
    int*   boff   = (int*)  alloc(64 * 4);
    if (off > ws_size) return;

    hipMemsetAsync(deg, 0, (size_t)N_NODES * 4, stream);
    hipMemsetAsync(denom, 0, NHEADS * 4, stream);

    k_pack_w<<<(NOUT * NFEAT + 255) / 256, 256, 0, stream>>>(w1, proj_w, WpT);

    dim3 gg((N_NODES + 127) / 128, 3);
    k_gemm<<<gg, 256, 0, stream>>>(x, WpT, nb);

    k_edges<<<(ET_EDGES + 255) / 256, 256, 0, stream>>>(nb, ei, eww, b1v, w2, b2v,
                                                        pbuf, denom, deg);
    k_scan1<<<NBLK_SCAN, 1024, 0, stream>>>(deg, rowptr, bsum);
    k_scan2<<<1, 64, 0, stream>>>(bsum, boff, rowptr, denom, dinv);
    k_scan3<<<(N_NODES + 255) / 256, 256, 0, stream>>>(rowptr, boff, cursor);
    k_scatter<<<(ET_EDGES + 255) / 256, 256, 0, stream>>>(ei, pbuf, dinv, cursor, wbuf, srcb);
    k_agg<<<(N_NODES + 3) / 4, 256, 0, stream>>>(nb, wbuf, srcb, rowptr,
                                                 proj_b, ln_g, ln_b, out);
}

// Round 4
// 256.365 us; speedup vs baseline: 2.3861x; 1.1281x over previous
//
#include <hip/hip_runtime.h>
#include <hip/hip_bf16.h>

#define N_NODES 50000
#define N_EDGES 800000
#define ET_EDGES (N_EDGES + N_NODES)   // 850000
#define NFEAT 128
#define NCLASS 64
#define NHEADS 8
#define HIDDEN 32
#define NAB 64            // nb row: a(32) | b(32)
#define KAGG 1024         // 8 heads * 128 feat
typedef unsigned short u16;
typedef unsigned int u32;

typedef __attribute__((ext_vector_type(8))) short bf16x8;
typedef __attribute__((ext_vector_type(4))) float f32x4;

static __device__ __forceinline__ u16 f2bf(float f) {
    u32 u = __float_as_uint(f);
    return (u16)((u + 0x7fffu + ((u >> 16) & 1u)) >> 16);  // RNE
}
static __device__ __forceinline__ u32 pack2bf(float lo, float hi) {
    return (u32)f2bf(lo) | ((u32)f2bf(hi) << 16);
}
static __device__ __forceinline__ float bfl(u32 u) { return __uint_as_float(u << 16); }
static __device__ __forceinline__ float bfh(u32 u) { return __uint_as_float(u & 0xffff0000u); }

// ---- pack WpT[o][k] bf16 [64][128]: o<32: w1 top half col o; o>=32: w1 bottom half ----
__global__ void k_pack_w(const float* __restrict__ w1, u16* __restrict__ WpT) {
    int idx = blockIdx.x * 256 + threadIdx.x;
    if (idx >= NAB * NFEAT) return;
    int o = idx / NFEAT, k = idx % NFEAT;
    float v = (o < HIDDEN) ? w1[k * HIDDEN + o]
                           : w1[(NFEAT + k) * HIDDEN + (o - HIDDEN)];
    WpT[idx] = f2bf(v);
}

// ---- pack pwT[c][k] bf16 [64][1024] from proj_w[k][c] ----
__global__ void k_pack_pw(const float* __restrict__ proj_w, u16* __restrict__ pwT) {
    int idx = blockIdx.x * 256 + threadIdx.x;
    if (idx >= NCLASS * KAGG) return;
    int c = idx >> 10, k = idx & (KAGG - 1);
    pwT[idx] = f2bf(proj_w[(size_t)k * NCLASS + c]);
}

// ---- GEMM1: nb[N][64] = x[N][128] @ WpT^T ; write-through xb (bf16 copy of x) ----
#define ROWP 136
__global__ __launch_bounds__(256) void k_gemm(const float* __restrict__ x,
                                              const u16* __restrict__ WpT,
                                              u16* __restrict__ nb,
                                              u16* __restrict__ xb) {
    __shared__ __align__(16) u16 As[128 * ROWP];
    __shared__ __align__(16) u16 Bs[64 * ROWP];
    int tid = threadIdx.x;
    int m0 = blockIdx.x * 128;
    int wv = tid >> 6, l = tid & 63, lr = l & 15, lg = l >> 4;

#pragma unroll
    for (int p = 0; p < 8; ++p) {
        int idx = tid + p * 256;
        int row = idx >> 4, fo = idx & 15;
        int gm = m0 + row;
        float4 f0 = make_float4(0.f,0.f,0.f,0.f), f1 = f0;
        if (gm < N_NODES) {
            const float* xp = x + (size_t)gm * NFEAT + fo * 8;
            f0 = *(const float4*)xp;
            f1 = *(const float4*)(xp + 4);
        }
        uint4 v;
        v.x = pack2bf(f0.x, f0.y); v.y = pack2bf(f0.z, f0.w);
        v.z = pack2bf(f1.x, f1.y); v.w = pack2bf(f1.z, f1.w);
        *(uint4*)&As[row * ROWP + fo * 8] = v;
        if (gm < N_NODES) *(uint4*)(xb + (size_t)gm * NFEAT + fo * 8) = v;
    }
#pragma unroll
    for (int p = 0; p < 4; ++p) {
        int idx = tid + p * 256;
        int col = idx >> 4, fo = idx & 15;
        *(uint4*)&Bs[col * ROWP + fo * 8] = *(const uint4*)(WpT + (size_t)col * NFEAT + fo * 8);
    }
    __syncthreads();
    union FR { uint4 q; bf16x8 v; };
    f32x4 acc[2][4];
#pragma unroll
    for (int fr = 0; fr < 2; ++fr)
#pragma unroll
        for (int fc = 0; fc < 4; ++fc) acc[fr][fc] = (f32x4){0.f, 0.f, 0.f, 0.f};
#pragma unroll
    for (int ks = 0; ks < 4; ++ks) {
        int k0 = ks * 32;
        FR a0, a1, b0, b1, b2, b3;
        a0.q = *(const uint4*)&As[(wv * 32 + 0  + lr) * ROWP + k0 + 8 * lg];
        a1.q = *(const uint4*)&As[(wv * 32 + 16 + lr) * ROWP + k0 + 8 * lg];
        b0.q = *(const uint4*)&Bs[(0  + lr) * ROWP + k0 + 8 * lg];
        b1.q = *(const uint4*)&Bs[(16 + lr) * ROWP + k0 + 8 * lg];
        b2.q = *(const uint4*)&Bs[(32 + lr) * ROWP + k0 + 8 * lg];
        b3.q = *(const uint4*)&Bs[(48 + lr) * ROWP + k0 + 8 * lg];
        acc[0][0] = __builtin_amdgcn_mfma_f32_16x16x32_bf16(a0.v, b0.v, acc[0][0], 0, 0, 0);
        acc[0][1] = __builtin_amdgcn_mfma_f32_16x16x32_bf16(a0.v, b1.v, acc[0][1], 0, 0, 0);
        acc[0][2] = __builtin_amdgcn_mfma_f32_16x16x32_bf16(a0.v, b2.v, acc[0][2], 0, 0, 0);
        acc[0][3] = __builtin_amdgcn_mfma_f32_16x16x32_bf16(a0.v, b3.v, acc[0][3], 0, 0, 0);
        acc[1][0] = __builtin_amdgcn_mfma_f32_16x16x32_bf16(a1.v, b0.v, acc[1][0], 0, 0, 0);
        acc[1][1] = __builtin_amdgcn_mfma_f32_16x16x32_bf16(a1.v, b1.v, acc[1][1], 0, 0, 0);
        acc[1][2] = __builtin_amdgcn_mfma_f32_16x16x32_bf16(a1.v, b2.v, acc[1][2], 0, 0, 0);
        acc[1][3] = __builtin_amdgcn_mfma_f32_16x16x32_bf16(a1.v, b3.v, acc[1][3], 0, 0, 0);
    }
    // D[row = wv*32+fr*16+4*lg+r][col = fc*16+lr]
#pragma unroll
    for (int fr = 0; fr < 2; ++fr)
#pragma unroll
        for (int fc = 0; fc < 4; ++fc)
#pragma unroll
            for (int r = 0; r < 4; ++r) {
                int gm = m0 + wv * 32 + fr * 16 + 4 * lg + r;
                if (gm < N_NODES)
                    nb[(size_t)gm * NAB + fc * 16 + lr] = f2bf(acc[fr][fc][r]);
            }
}

// ---- per-edge MLP + gate + exp; deg histogram; softmax denom partials ----
__global__ __launch_bounds__(256) void k_edges(const u16* __restrict__ nb,
                                               const int* __restrict__ ei,
                                               const float* __restrict__ eww,
                                               const float* __restrict__ b1v,
                                               const float* __restrict__ w2,
                                               const float* __restrict__ b2v,
                                               float* __restrict__ pbuf,
                                               float* __restrict__ denom,
                                               int* __restrict__ deg) {
    int e = blockIdx.x * 256 + threadIdx.x;
    bool valid = e < ET_EDGES;
    int s = 0, d = 0;
    if (valid) {
        if (e < N_EDGES) { s = ei[e]; d = ei[N_EDGES + e]; }
        else             { s = d = e - N_EDGES; }
    }
    const uint4* ap = (const uint4*)(nb + (size_t)s * NAB);
    const uint4* bp = (const uint4*)(nb + (size_t)d * NAB + HIDDEN);
    float h[HIDDEN];
#pragma unroll
    for (int q = 0; q < 4; ++q) {
        uint4 ua = ap[q], ub = bp[q];
        h[q*8+0] = fmaxf(bfl(ua.x) + bfl(ub.x) + b1v[q*8+0], 0.f);
        h[q*8+1] = fmaxf(bfh(ua.x) + bfh(ub.x) + b1v[q*8+1], 0.f);
        h[q*8+2] = fmaxf(bfl(ua.y) + bfl(ub.y) + b1v[q*8+2], 0.f);
        h[q*8+3] = fmaxf(bfh(ua.y) + bfh(ub.y) + b1v[q*8+3], 0.f);
        h[q*8+4] = fmaxf(bfl(ua.z) + bfl(ub.z) + b1v[q*8+4], 0.f);
        h[q*8+5] = fmaxf(bfh(ua.z) + bfh(ub.z) + b1v[q*8+5], 0.f);
        h[q*8+6] = fmaxf(bfl(ua.w) + bfl(ub.w) + b1v[q*8+6], 0.f);
        h[q*8+7] = fmaxf(bfh(ua.w) + bfh(ub.w) + b1v[q*8+7], 0.f);
    }
    float z[NHEADS];
#pragma unroll
    for (int t = 0; t < NHEADS; ++t) z[t] = b2v[t];
#pragma unroll
    for (int j = 0; j < HIDDEN; ++j)
#pragma unroll
        for (int t = 0; t < NHEADS; ++t) z[t] = fmaf(h[j], w2[j * NHEADS + t], z[t]);

    float pe[NHEADS];
#pragma unroll
    for (int t = 0; t < NHEADS; ++t) {
        float dyn = 1.f / (1.f + __expf(-z[t]));
        float w   = valid ? eww[(size_t)t * ET_EDGES + e] : 0.f;
        float tw  = w * dyn;
        tw = tw > 0.f ? tw : 0.01f * tw;
        pe[t] = valid ? __expf(tw) : 0.f;
    }
    if (valid) {
        float* pr = pbuf + (size_t)e * 8;
        *(float4*)pr       = make_float4(pe[0], pe[1], pe[2], pe[3]);
        *(float4*)(pr + 4) = make_float4(pe[4], pe[5], pe[6], pe[7]);
        atomicAdd(&deg[d], 1);
    }
    __shared__ float blk[NHEADS];
    if (threadIdx.x < NHEADS) blk[threadIdx.x] = 0.f;
    __syncthreads();
    int lane = threadIdx.x & 63;
#pragma unroll
    for (int t = 0; t < NHEADS; ++t) {
        float v = pe[t];
        for (int off = 32; off > 0; off >>= 1) v += __shfl_xor(v, off);
        if (lane == 0) atomicAdd(&blk[t], v);
    }
    __syncthreads();
    if (threadIdx.x < NHEADS) atomicAdd(&denom[threadIdx.x], blk[threadIdx.x]);
}

// ---- scan (3 kernels) ----
__global__ __launch_bounds__(1024) void k_scan1(const int* __restrict__ deg,
                                                int* __restrict__ rowptr,
                                                int* __restrict__ bsum) {
    __shared__ int sd[1024];
    int tid = threadIdx.x;
    int i = blockIdx.x * 1024 + tid;
    int v = (i < N_NODES) ? deg[i] : 0;
    sd[tid] = v;
    __syncthreads();
    for (int off = 1; off < 1024; off <<= 1) {
        int t = (tid >= off) ? sd[tid - off] : 0;
        __syncthreads();
        sd[tid] += t;
        __syncthreads();
    }
    if (i < N_NODES) rowptr[i] = sd[tid] - v;
    if (tid == 1023) bsum[blockIdx.x] = sd[1023];
}
#define NBLK_SCAN 49
__global__ __launch_bounds__(64) void k_scan2(const int* __restrict__ bsum,
                                              int* __restrict__ boff,
                                              int* __restrict__ rowptr,
                                              const float* __restrict__ denom,
                                              float* __restrict__ dinv) {
    int l = threadIdx.x;
    int orig = (l < NBLK_SCAN) ? bsum[l] : 0;
    int v = orig;
    for (int off = 1; off < 64; off <<= 1) {
        int t = __shfl_up(v, off);
        if (l >= off) v += t;
    }
    if (l < NBLK_SCAN) boff[l] = v - orig;
    if (l == 63) rowptr[N_NODES] = v;
    if (l < NHEADS) dinv[l] = 1.0f / denom[l];
}
__global__ __launch_bounds__(256) void k_scan3(int* __restrict__ rowptr,
                                               const int* __restrict__ boff,
                                               int* __restrict__ cursor) {
    int i = blockIdx.x * 256 + threadIdx.x;
    if (i >= N_NODES) return;
    int r = rowptr[i] + boff[i >> 10];
    rowptr[i] = r;
    cursor[i] = r;
}

// ---- scatter: normalize weights, pack bf16, write CSR-ordered wbuf + srcb ----
__global__ __launch_bounds__(256) void k_scatter(const int* __restrict__ ei,
                                                 const float* __restrict__ pbuf,
                                                 const float* __restrict__ dinv,
                                                 int* __restrict__ cursor,
                                                 u16* __restrict__ wbuf,
                                                 int* __restrict__ srcb) {
    int e = blockIdx.x * 256 + threadIdx.x;
    if (e >= ET_EDGES) return;
    int s, d;
    if (e < N_EDGES) { s = ei[e]; d = ei[N_EDGES + e]; }
    else             { s = d = e - N_EDGES; }
    const float4* pp = (const float4*)(pbuf + (size_t)e * 8);
    float4 p0 = pp[0], p1 = pp[1];
    uint4 w;
    w.x = pack2bf(p0.x * dinv[0], p0.y * dinv[1]);
    w.y = pack2bf(p0.z * dinv[2], p0.w * dinv[3]);
    w.z = pack2bf(p1.x * dinv[4], p1.y * dinv[5]);
    w.w = pack2bf(p1.z * dinv[6], p1.w * dinv[7]);
    int pos = atomicAdd(&cursor[d], 1);
    *(uint4*)(wbuf + (size_t)pos * 8) = w;
    srcb[pos] = s;
}

// ---- aggregate in feature space: aggx[n][h*128+f] = sum_e w[h] * xb[src][f] ----
static __device__ __forceinline__ void edge_acc(float (&acc)[8][2], uint4 wq, u32 xu) {
    float x0 = bfl(xu), x1 = bfh(xu);
    float w[8] = { bfl(wq.x), bfh(wq.x), bfl(wq.y), bfh(wq.y),
                   bfl(wq.z), bfh(wq.z), bfl(wq.w), bfh(wq.w) };
#pragma unroll
    for (int h = 0; h < 8; ++h) {
        acc[h][0] = fmaf(w[h], x0, acc[h][0]);
        acc[h][1] = fmaf(w[h], x1, acc[h][1]);
    }
}
__global__ __launch_bounds__(256) void k_agg(const u16* __restrict__ xb,
                                             const u16* __restrict__ wbuf,
                                             const int* __restrict__ srcb,
                                             const int* __restrict__ rowptr,
                                             u16* __restrict__ aggx) {
    int wv = threadIdx.x >> 6, lane = threadIdx.x & 63;
    int n = blockIdx.x * 4 + wv;
    if (n >= N_NODES) return;
    float acc[8][2];
#pragma unroll
    for (int h = 0; h < 8; ++h) { acc[h][0] = 0.f; acc[h][1] = 0.f; }
    int beg = rowptr[n], end = rowptr[n + 1];
    int idx = beg;
    for (; idx + 2 <= end; idx += 2) {
        int s0 = srcb[idx], s1 = srcb[idx + 1];
        uint4 w0 = *(const uint4*)(wbuf + (size_t)idx * 8);
        uint4 w1 = *(const uint4*)(wbuf + (size_t)(idx + 1) * 8);
        u32 x0 = *(const u32*)(xb + (size_t)s0 * NFEAT + 2 * lane);
        u32 x1 = *(const u32*)(xb + (size_t)s1 * NFEAT + 2 * lane);
        edge_acc(acc, w0, x0);
        edge_acc(acc, w1, x1);
    }
    if (idx < end) {
        int s0 = srcb[idx];
        uint4 w0 = *(const uint4*)(wbuf + (size_t)idx * 8);
        u32 x0 = *(const u32*)(xb + (size_t)s0 * NFEAT + 2 * lane);
        edge_acc(acc, w0, x0);
    }
    u16* dst = aggx + (size_t)n * KAGG + 2 * lane;
#pragma unroll
    for (int h = 0; h < 8; ++h)
        *(u32*)(dst + h * NFEAT) = pack2bf(acc[h][0], acc[h][1]);
}

// ---- GEMM2 + bias + LayerNorm: out[N][64] = LN(aggx[N][1024] @ pwT^T + proj_b) ----
__global__ __launch_bounds__(256) void k_out(const u16* __restrict__ aggx,
                                             const u16* __restrict__ pwT,
                                             const float* __restrict__ proj_b,
                                             const float* __restrict__ ln_g,
                                             const float* __restrict__ ln_b,
                                             float* __restrict__ out) {
    __shared__ __align__(16) u16 As[128 * ROWP];
    __shared__ __align__(16) u16 Bs[64 * ROWP];
    int tid = threadIdx.x;
    int m0 = blockIdx.x * 128;
    int wv = tid >> 6, l = tid & 63, lr = l & 15, lg = l >> 4;
    union FR { uint4 q; bf16x8 v; };
    f32x4 acc[2][4];
#pragma unroll
    for (int fr = 0; fr < 2; ++fr)
#pragma unroll
        for (int fc = 0; fc < 4; ++fc) acc[fr][fc] = (f32x4){0.f, 0.f, 0.f, 0.f};

    for (int kt = 0; kt < 8; ++kt) {
        int kb = kt * 128;
        __syncthreads();
#pragma unroll
        for (int p = 0; p < 8; ++p) {
            int idx = tid + p * 256;
            int row = idx >> 4, fo = idx & 15;
            int gm = m0 + row;
            uint4 v = make_uint4(0u, 0u, 0u, 0u);
            if (gm < N_NODES) v = *(const uint4*)(aggx + (size_t)gm * KAGG + kb + fo * 8);
            *(uint4*)&As[row * ROWP + fo * 8] = v;
        }
#pragma unroll
        for (int p = 0; p < 4; ++p) {
            int idx = tid + p * 256;
            int col = idx >> 4, fo = idx & 15;
            *(uint4*)&Bs[col * ROWP + fo * 8] =
                *(const uint4*)(pwT + (size_t)col * KAGG + kb + fo * 8);
        }
        __syncthreads();
#pragma unroll
        for (int ks = 0; ks < 4; ++ks) {
            int k0 = ks * 32;
            FR a0, a1, b0, b1, b2, b3;
            a0.q = *(const uint4*)&As[(wv * 32 + 0  + lr) * ROWP + k0 + 8 * lg];
            a1.q = *(const uint4*)&As[(wv * 32 + 16 + lr) * ROWP + k0 + 8 * lg];
            b0.q = *(const uint4*)&Bs[(0  + lr) * ROWP + k0 + 8 * lg];
            b1.q = *(const uint4*)&Bs[(16 + lr) * ROWP + k0 + 8 * lg];
            b2.q = *(const uint4*)&Bs[(32 + lr) * ROWP + k0 + 8 * lg];
            b3.q = *(const uint4*)&Bs[(48 + lr) * ROWP + k0 + 8 * lg];
            acc[0][0] = __builtin_amdgcn_mfma_f32_16x16x32_bf16(a0.v, b0.v, acc[0][0], 0, 0, 0);
            acc[0][1] = __builtin_amdgcn_mfma_f32_16x16x32_bf16(a0.v, b1.v, acc[0][1], 0, 0, 0);
            acc[0][2] = __builtin_amdgcn_mfma_f32_16x16x32_bf16(a0.v, b2.v, acc[0][2], 0, 0, 0);
            acc[0][3] = __builtin_amdgcn_mfma_f32_16x16x32_bf16(a0.v, b3.v, acc[0][3], 0, 0, 0);
            acc[1][0] = __builtin_amdgcn_mfma_f32_16x16x32_bf16(a1.v, b0.v, acc[1][0], 0, 0, 0);
            acc[1][1] = __builtin_amdgcn_mfma_f32_16x16x32_bf16(a1.v, b1.v, acc[1][1], 0, 0, 0);
            acc[1][2] = __builtin_amdgcn_mfma_f32_16x16x32_bf16(a1.v, b2.v, acc[1][2], 0, 0, 0);
            acc[1][3] = __builtin_amdgcn_mfma_f32_16x16x32_bf16(a1.v, b3.v, acc[1][3], 0, 0, 0);
        }
    }
    // per-lane col set: {fc*16+lr}; per-(fr,r) row = m0+wv*32+fr*16+4*lg+r (16 lanes share it)
    float pb4[4], g4[4], b4[4];
#pragma unroll
    for (int fc = 0; fc < 4; ++fc) {
        pb4[fc] = proj_b[fc * 16 + lr];
        g4[fc]  = ln_g[fc * 16 + lr];
        b4[fc]  = ln_b[fc * 16 + lr];
    }
#pragma unroll
    for (int fr = 0; fr < 2; ++fr)
#pragma unroll
        for (int r = 0; r < 4; ++r) {
            int gm = m0 + wv * 32 + fr * 16 + 4 * lg + r;
            float v[4];
#pragma unroll
            for (int fc = 0; fc < 4; ++fc) v[fc] = acc[fr][fc][r] + pb4[fc];
            float s = v[0] + v[1] + v[2] + v[3];
            s += __shfl_xor(s, 1); s += __shfl_xor(s, 2);
            s += __shfl_xor(s, 4); s += __shfl_xor(s, 8);
            float mu = s * (1.f / 64.f);
            float q = 0.f;
#pragma unroll
            for (int fc = 0; fc < 4; ++fc) { v[fc] -= mu; q = fmaf(v[fc], v[fc], q); }
            q += __shfl_xor(q, 1); q += __shfl_xor(q, 2);
            q += __shfl_xor(q, 4); q += __shfl_xor(q, 8);
            float inv = rsqrtf(q * (1.f / 64.f) + 1e-5f);
            if (gm < N_NODES) {
#pragma unroll
                for (int fc = 0; fc < 4; ++fc)
                    out[(size_t)gm * NCLASS + fc * 16 + lr] = v[fc] * inv * g4[fc] + b4[fc];
            }
        }
}

extern "C" void kernel_launch(void* const* d_in, const int* in_sizes, int n_in,
                              void* d_out, int out_size, void* d_ws, size_t ws_size,
                              hipStream_t stream) {
    const float* x      = (const float*)d_in[0];
    const int*   ei     = (const int*)  d_in[1];
    const float* eww    = (const float*)d_in[2];
    const float* w1     = (const float*)d_in[3];
    const float* b1v    = (const float*)d_in[4];
    const float* w2     = (const float*)d_in[5];
    const float* b2v    = (const float*)d_in[6];
    const float* proj_w = (const float*)d_in[7];
    const float* proj_b = (const float*)d_in[8];
    const float* ln_g   = (const float*)d_in[9];
    const float* ln_b   = (const float*)d_in[10];
    float* out = (float*)d_out;

    char* ws = (char*)d_ws;
    size_t off = 0;
    auto alloc = [&](size_t bytes) -> void* {
        void* p = ws + off;
        off = (off + bytes + 255) & ~(size_t)255;
        return p;
    };
    // aggx (live: k_agg..k_out) aliases pbuf (live: k_edges..k_scatter) — disjoint lifetimes
    u16*   aggx   = (u16*)  alloc((size_t)N_NODES * KAGG * 2);    // 102.4 MB
    float* pbuf   = (float*)aggx;                                 // first 27.2 MB of aggx
    u16*   nb     = (u16*)  alloc((size_t)N_NODES * NAB * 2);     // 6.4 MB
    u16*   xb     = (u16*)  alloc((size_t)N_NODES * NFEAT * 2);   // 12.8 MB
    u16*   WpT    = (u16*)  alloc((size_t)NAB * NFEAT * 2);       // 16 KB
    u16*   pwT    = (u16*)  alloc((size_t)NCLASS * KAGG * 2);     // 128 KB
    u16*   wbuf   = (u16*)  alloc((size_t)ET_EDGES * 8 * 2);      // 13.6 MB
    int*   srcb   = (int*)  alloc((size_t)ET_EDGES * 4);          // 3.4 MB
    float* denom  = (float*)alloc(NHEADS * 4);
    float* dinv   = (float*)alloc(NHEADS * 4);
    int*   deg    = (int*)  alloc((size_t)N_NODES * 4);
    int*   rowptr = (int*)  alloc((size_t)(N_NODES + 1) * 4);
    int*   cursor = (int*)  alloc((size_t)N_NODES * 4);
    int*   bsum   = (int*)  alloc(64 * 4);
    int*   boff   = (int*)  alloc(64 * 4);
    if (off > ws_size) return;

    hipMemsetAsync(deg, 0, (size_t)N_NODES * 4, stream);
    hipMemsetAsync(denom, 0, NHEADS * 4, stream);

    k_pack_w<<<(NAB * NFEAT + 255) / 256, 256, 0, stream>>>(w1, WpT);
    k_pack_pw<<<(NCLASS * KAGG + 255) / 256, 256, 0, stream>>>(proj_w, pwT);

    k_gemm<<<(N_NODES + 127) / 128, 256, 0, stream>>>(x, WpT, nb, xb);

    k_edges<<<(ET_EDGES + 255) / 256, 256, 0, stream>>>(nb, ei, eww, b1v, w2, b2v,
                                                        pbuf, denom, deg);
    k_scan1<<<NBLK_SCAN, 1024, 0, stream>>>(deg, rowptr, bsum);
    k_scan2<<<1, 64, 0, stream>>>(bsum, boff, rowptr, denom, dinv);
    k_scan3<<<(N_NODES + 255) / 256, 256, 0, stream>>>(rowptr, boff, cursor);
    k_scatter<<<(ET_EDGES + 255) / 256, 256, 0, stream>>>(ei, pbuf, dinv, cursor, wbuf, srcb);
    k_agg<<<(N_NODES + 3) / 4, 256, 0, stream>>>(xb, wbuf, srcb, rowptr, aggx);
    k_out<<<(N_NODES + 127) / 128, 256, 0, stream>>>(aggx, pwT, proj_b, ln_g, ln_b, out);
}

// Round 5
// 242.391 us; speedup vs baseline: 2.5237x; 1.0576x over previous
//
#include <hip/hip_runtime.h>
#include <hip/hip_bf16.h>

#define N_NODES 50000
#define N_EDGES 800000
#define ET_EDGES (N_EDGES + N_NODES)   // 850000
#define EHALF (ET_EDGES / 2)           // 425000 (< N_EDGES: first-half edges are never self-loops)
#define NFEAT 128
#define NCLASS 64
#define NHEADS 8
#define HIDDEN 32
#define NAB 64            // nb row: a(32) | b(32)  (b has b1 folded in)
#define KAGG 1024         // 8 heads * 128 feat
typedef unsigned short u16;
typedef unsigned int u32;

typedef __attribute__((ext_vector_type(8))) short bf16x8;
typedef __attribute__((ext_vector_type(4))) float f32x4;

static __device__ __forceinline__ u16 f2bf(float f) {
    u32 u = __float_as_uint(f);
    return (u16)((u + 0x7fffu + ((u >> 16) & 1u)) >> 16);  // RNE
}
static __device__ __forceinline__ u32 pack2bf(float lo, float hi) {
    return (u32)f2bf(lo) | ((u32)f2bf(hi) << 16);
}
static __device__ __forceinline__ float bfl(u32 u) { return __uint_as_float(u << 16); }
static __device__ __forceinline__ float bfh(u32 u) { return __uint_as_float(u & 0xffff0000u); }

// ---- pack WpT[o][k] bf16 [64][128]: o<32: w1 top half col o; o>=32: w1 bottom half ----
__global__ void k_pack_w(const float* __restrict__ w1, u16* __restrict__ WpT) {
    int idx = blockIdx.x * 256 + threadIdx.x;
    if (idx >= NAB * NFEAT) return;
    int o = idx / NFEAT, k = idx % NFEAT;
    float v = (o < HIDDEN) ? w1[k * HIDDEN + o]
                           : w1[(NFEAT + k) * HIDDEN + (o - HIDDEN)];
    WpT[idx] = f2bf(v);
}

// ---- pack pwT[c][k] bf16 [64][1024] from proj_w[k][c] ----
__global__ void k_pack_pw(const float* __restrict__ proj_w, u16* __restrict__ pwT) {
    int idx = blockIdx.x * 256 + threadIdx.x;
    if (idx >= NCLASS * KAGG) return;
    int c = idx >> 10, k = idx & (KAGG - 1);
    pwT[idx] = f2bf(proj_w[(size_t)k * NCLASS + c]);
}

// ---- degree histogram from dst row of ei (real edges only; self-loops via +1 in scan) ----
__global__ __launch_bounds__(256) void k_deg(const int* __restrict__ ei, int* __restrict__ deg) {
    int e = blockIdx.x * 256 + threadIdx.x;
    if (e >= N_EDGES) return;
    atomicAdd(&deg[ei[N_EDGES + e]], 1);
}

// ---- GEMM1: nb[N][64] = x[N][128] @ WpT^T (+b1 on b-cols); write-through xb ----
#define ROWP 136
__global__ __launch_bounds__(256) void k_gemm(const float* __restrict__ x,
                                              const u16* __restrict__ WpT,
                                              const float* __restrict__ b1v,
                                              u16* __restrict__ nb,
                                              u16* __restrict__ xb) {
    __shared__ __align__(16) u16 As[128 * ROWP];
    __shared__ __align__(16) u16 Bs[64 * ROWP];
    int tid = threadIdx.x;
    int m0 = blockIdx.x * 128;
    int wv = tid >> 6, l = tid & 63, lr = l & 15, lg = l >> 4;

#pragma unroll
    for (int p = 0; p < 8; ++p) {
        int idx = tid + p * 256;
        int row = idx >> 4, fo = idx & 15;
        int gm = m0 + row;
        float4 f0 = make_float4(0.f,0.f,0.f,0.f), f1 = f0;
        if (gm < N_NODES) {
            const float* xp = x + (size_t)gm * NFEAT + fo * 8;
            f0 = *(const float4*)xp;
            f1 = *(const float4*)(xp + 4);
        }
        uint4 v;
        v.x = pack2bf(f0.x, f0.y); v.y = pack2bf(f0.z, f0.w);
        v.z = pack2bf(f1.x, f1.y); v.w = pack2bf(f1.z, f1.w);
        *(uint4*)&As[row * ROWP + fo * 8] = v;
        if (gm < N_NODES) *(uint4*)(xb + (size_t)gm * NFEAT + fo * 8) = v;
    }
#pragma unroll
    for (int p = 0; p < 4; ++p) {
        int idx = tid + p * 256;
        int col = idx >> 4, fo = idx & 15;
        *(uint4*)&Bs[col * ROWP + fo * 8] = *(const uint4*)(WpT + (size_t)col * NFEAT + fo * 8);
    }
    __syncthreads();
    union FR { uint4 q; bf16x8 v; };
    f32x4 acc[2][4];
#pragma unroll
    for (int fr = 0; fr < 2; ++fr)
#pragma unroll
        for (int fc = 0; fc < 4; ++fc) acc[fr][fc] = (f32x4){0.f, 0.f, 0.f, 0.f};
#pragma unroll
    for (int ks = 0; ks < 4; ++ks) {
        int k0 = ks * 32;
        FR a0, a1, b0, b1, b2, b3;
        a0.q = *(const uint4*)&As[(wv * 32 + 0  + lr) * ROWP + k0 + 8 * lg];
        a1.q = *(const uint4*)&As[(wv * 32 + 16 + lr) * ROWP + k0 + 8 * lg];
        b0.q = *(const uint4*)&Bs[(0  + lr) * ROWP + k0 + 8 * lg];
        b1.q = *(const uint4*)&Bs[(16 + lr) * ROWP + k0 + 8 * lg];
        b2.q = *(const uint4*)&Bs[(32 + lr) * ROWP + k0 + 8 * lg];
        b3.q = *(const uint4*)&Bs[(48 + lr) * ROWP + k0 + 8 * lg];
        acc[0][0] = __builtin_amdgcn_mfma_f32_16x16x32_bf16(a0.v, b0.v, acc[0][0], 0, 0, 0);
        acc[0][1] = __builtin_amdgcn_mfma_f32_16x16x32_bf16(a0.v, b1.v, acc[0][1], 0, 0, 0);
        acc[0][2] = __builtin_amdgcn_mfma_f32_16x16x32_bf16(a0.v, b2.v, acc[0][2], 0, 0, 0);
        acc[0][3] = __builtin_amdgcn_mfma_f32_16x16x32_bf16(a0.v, b3.v, acc[0][3], 0, 0, 0);
        acc[1][0] = __builtin_amdgcn_mfma_f32_16x16x32_bf16(a1.v, b0.v, acc[1][0], 0, 0, 0);
        acc[1][1] = __builtin_amdgcn_mfma_f32_16x16x32_bf16(a1.v, b1.v, acc[1][1], 0, 0, 0);
        acc[1][2] = __builtin_amdgcn_mfma_f32_16x16x32_bf16(a1.v, b2.v, acc[1][2], 0, 0, 0);
        acc[1][3] = __builtin_amdgcn_mfma_f32_16x16x32_bf16(a1.v, b3.v, acc[1][3], 0, 0, 0);
    }
    // D[row = wv*32+fr*16+4*lg+r][col = fc*16+lr] ; fold b1 into cols 32..63
    float badd[4];
    badd[0] = 0.f; badd[1] = 0.f; badd[2] = b1v[lr]; badd[3] = b1v[16 + lr];
#pragma unroll
    for (int fr = 0; fr < 2; ++fr)
#pragma unroll
        for (int fc = 0; fc < 4; ++fc)
#pragma unroll
            for (int r = 0; r < 4; ++r) {
                int gm = m0 + wv * 32 + fr * 16 + 4 * lg + r;
                if (gm < N_NODES)
                    nb[(size_t)gm * NAB + fc * 16 + lr] = f2bf(acc[fr][fc][r] + badd[fc]);
            }
}

// ---- scan (3 kernels); scan1 adds +1 per node for the self-loop ----
__global__ __launch_bounds__(1024) void k_scan1(const int* __restrict__ deg,
                                                int* __restrict__ rowptr,
                                                int* __restrict__ bsum) {
    __shared__ int sd[1024];
    int tid = threadIdx.x;
    int i = blockIdx.x * 1024 + tid;
    int v = (i < N_NODES) ? deg[i] + 1 : 0;
    sd[tid] = v;
    __syncthreads();
    for (int off = 1; off < 1024; off <<= 1) {
        int t = (tid >= off) ? sd[tid - off] : 0;
        __syncthreads();
        sd[tid] += t;
        __syncthreads();
    }
    if (i < N_NODES) rowptr[i] = sd[tid] - v;
    if (tid == 1023) bsum[blockIdx.x] = sd[1023];
}
#define NBLK_SCAN 49
__global__ __launch_bounds__(64) void k_scan2(const int* __restrict__ bsum,
                                              int* __restrict__ boff,
                                              int* __restrict__ rowptr) {
    int l = threadIdx.x;
    int orig = (l < NBLK_SCAN) ? bsum[l] : 0;
    int v = orig;
    for (int off = 1; off < 64; off <<= 1) {
        int t = __shfl_up(v, off);
        if (l >= off) v += t;
    }
    if (l < NBLK_SCAN) boff[l] = v - orig;
    if (l == 63) rowptr[N_NODES] = v;
}
__global__ __launch_bounds__(256) void k_scan3(int* __restrict__ rowptr,
                                               const int* __restrict__ boff,
                                               int* __restrict__ cursor) {
    int i = blockIdx.x * 256 + threadIdx.x;
    if (i >= N_NODES) return;
    int r = rowptr[i] + boff[i >> 10];
    rowptr[i] = r;
    cursor[i] = r;
}

// ---- fused per-edge MLP + gate + exp + CSR scatter; 2 edges per thread ----
static __device__ __forceinline__ void mk_h(const uint4 (&A)[4], const uint4 (&B)[4],
                                            float (&h)[32]) {
#pragma unroll
    for (int q = 0; q < 4; ++q) {
        h[q*8+0] = fmaxf(bfl(A[q].x) + bfl(B[q].x), 0.f);
        h[q*8+1] = fmaxf(bfh(A[q].x) + bfh(B[q].x), 0.f);
        h[q*8+2] = fmaxf(bfl(A[q].y) + bfl(B[q].y), 0.f);
        h[q*8+3] = fmaxf(bfh(A[q].y) + bfh(B[q].y), 0.f);
        h[q*8+4] = fmaxf(bfl(A[q].z) + bfl(B[q].z), 0.f);
        h[q*8+5] = fmaxf(bfh(A[q].z) + bfh(B[q].z), 0.f);
        h[q*8+6] = fmaxf(bfl(A[q].w) + bfl(B[q].w), 0.f);
        h[q*8+7] = fmaxf(bfh(A[q].w) + bfh(B[q].w), 0.f);
    }
}
__global__ __launch_bounds__(256) void k_edges(const u16* __restrict__ nb,
                                               const int* __restrict__ ei,
                                               const float* __restrict__ eww,
                                               const float* __restrict__ w2,
                                               const float* __restrict__ b2v,
                                               int* __restrict__ cursor,
                                               u16* __restrict__ wbuf,
                                               int* __restrict__ srcb,
                                               float* __restrict__ denom) {
    int t0 = blockIdx.x * 256 + threadIdx.x;
    int e0 = t0, e1 = t0 + EHALF;
    bool valid = e0 < EHALF;
    int s0 = 0, d0 = 0, s1 = 0, d1 = 0;
    if (valid) {
        s0 = ei[e0]; d0 = ei[N_EDGES + e0];           // e0 < EHALF < N_EDGES: never self-loop
        if (e1 < N_EDGES) { s1 = ei[e1]; d1 = ei[N_EDGES + e1]; }
        else              { s1 = d1 = e1 - N_EDGES; }
    }
    // issue all 16 gathers up front (2 edges x (a-row + b-row) x 4 uint4)
    const uint4* a0p = (const uint4*)(nb + (size_t)s0 * NAB);
    const uint4* b0p = (const uint4*)(nb + (size_t)d0 * NAB + HIDDEN);
    const uint4* a1p = (const uint4*)(nb + (size_t)s1 * NAB);
    const uint4* b1p = (const uint4*)(nb + (size_t)d1 * NAB + HIDDEN);
    uint4 A0[4], B0[4], A1[4], B1[4];
#pragma unroll
    for (int q = 0; q < 4; ++q) { A0[q] = a0p[q]; B0[q] = b0p[q]; }
#pragma unroll
    for (int q = 0; q < 4; ++q) { A1[q] = a1p[q]; B1[q] = b1p[q]; }

    float h0[32], h1[32];
    mk_h(A0, B0, h0);
    mk_h(A1, B1, h1);

    float z0[8], z1[8];
#pragma unroll
    for (int t = 0; t < NHEADS; ++t) { z0[t] = 0.f; z1[t] = 0.f; }
#pragma unroll
    for (int j = 0; j < HIDDEN; ++j)
#pragma unroll
        for (int t = 0; t < NHEADS; ++t) {
            float w = w2[j * NHEADS + t];
            z0[t] = fmaf(h0[j], w, z0[t]);
            z1[t] = fmaf(h1[j], w, z1[t]);
        }

    int ee0 = valid ? e0 : 0, ee1 = valid ? e1 : 0;
    float pe0[8], pe1[8];
#pragma unroll
    for (int t = 0; t < NHEADS; ++t) {
        float dyn0 = 1.f / (1.f + __expf(-(z0[t] + b2v[t])));
        float dyn1 = 1.f / (1.f + __expf(-(z1[t] + b2v[t])));
        float tw0 = eww[(size_t)t * ET_EDGES + ee0] * dyn0;
        float tw1 = eww[(size_t)t * ET_EDGES + ee1] * dyn1;
        tw0 = fmaxf(tw0, 0.01f * tw0);                 // leaky_relu
        tw1 = fmaxf(tw1, 0.01f * tw1);
        pe0[t] = valid ? __expf(tw0) : 0.f;
        pe1[t] = valid ? __expf(tw1) : 0.f;
    }
    if (valid) {
        uint4 w0, w1;
        w0.x = pack2bf(pe0[0], pe0[1]); w0.y = pack2bf(pe0[2], pe0[3]);
        w0.z = pack2bf(pe0[4], pe0[5]); w0.w = pack2bf(pe0[6], pe0[7]);
        w1.x = pack2bf(pe1[0], pe1[1]); w1.y = pack2bf(pe1[2], pe1[3]);
        w1.z = pack2bf(pe1[4], pe1[5]); w1.w = pack2bf(pe1[6], pe1[7]);
        int p0 = atomicAdd(&cursor[d0], 1);
        int p1 = atomicAdd(&cursor[d1], 1);
        *(uint4*)(wbuf + (size_t)p0 * 8) = w0;
        srcb[p0] = s0;
        *(uint4*)(wbuf + (size_t)p1 * 8) = w1;
        srcb[p1] = s1;
    }
    // block-level denom partials
    __shared__ float blk[NHEADS];
    if (threadIdx.x < NHEADS) blk[threadIdx.x] = 0.f;
    __syncthreads();
    int lane = threadIdx.x & 63;
#pragma unroll
    for (int t = 0; t < NHEADS; ++t) {
        float v = pe0[t] + pe1[t];
        for (int off = 32; off > 0; off >>= 1) v += __shfl_xor(v, off);
        if (lane == 0) atomicAdd(&blk[t], v);
    }
    __syncthreads();
    if (threadIdx.x < NHEADS) atomicAdd(&denom[threadIdx.x], blk[threadIdx.x]);
}

// ---- aggregate in feature space: aggx[n][h*128+f] = dinv[h] * sum_e pe[h] * xb[src][f] ----
static __device__ __forceinline__ void edge_acc(float (&acc)[8][2], uint4 wq, u32 xu) {
    float x0 = bfl(xu), x1 = bfh(xu);
    float w[8] = { bfl(wq.x), bfh(wq.x), bfl(wq.y), bfh(wq.y),
                   bfl(wq.z), bfh(wq.z), bfl(wq.w), bfh(wq.w) };
#pragma unroll
    for (int h = 0; h < 8; ++h) {
        acc[h][0] = fmaf(w[h], x0, acc[h][0]);
        acc[h][1] = fmaf(w[h], x1, acc[h][1]);
    }
}
__global__ __launch_bounds__(256) void k_agg(const u16* __restrict__ xb,
                                             const u16* __restrict__ wbuf,
                                             const int* __restrict__ srcb,
                                             const int* __restrict__ rowptr,
                                             const float* __restrict__ denom,
                                             u16* __restrict__ aggx) {
    int wv = threadIdx.x >> 6, lane = threadIdx.x & 63;
    int n = blockIdx.x * 4 + wv;
    if (n >= N_NODES) return;
    float acc[8][2];
#pragma unroll
    for (int h = 0; h < 8; ++h) { acc[h][0] = 0.f; acc[h][1] = 0.f; }
    int beg = rowptr[n], end = rowptr[n + 1];
    int idx = beg;
    for (; idx + 2 <= end; idx += 2) {
        int s0 = srcb[idx], s1 = srcb[idx + 1];
        uint4 w0 = *(const uint4*)(wbuf + (size_t)idx * 8);
        uint4 w1 = *(const uint4*)(wbuf + (size_t)(idx + 1) * 8);
        u32 x0 = *(const u32*)(xb + (size_t)s0 * NFEAT + 2 * lane);
        u32 x1 = *(const u32*)(xb + (size_t)s1 * NFEAT + 2 * lane);
        edge_acc(acc, w0, x0);
        edge_acc(acc, w1, x1);
    }
    if (idx < end) {
        int s0 = srcb[idx];
        uint4 w0 = *(const uint4*)(wbuf + (size_t)idx * 8);
        u32 x0 = *(const u32*)(xb + (size_t)s0 * NFEAT + 2 * lane);
        edge_acc(acc, w0, x0);
    }
    u16* dst = aggx + (size_t)n * KAGG + 2 * lane;
#pragma unroll
    for (int h = 0; h < 8; ++h) {
        float di = 1.0f / denom[h];
        *(u32*)(dst + h * NFEAT) = pack2bf(acc[h][0] * di, acc[h][1] * di);
    }
}

// ---- GEMM2 + bias + LayerNorm: out[N][64] = LN(aggx[N][1024] @ pwT^T + proj_b) ----
__global__ __launch_bounds__(256) void k_out(const u16* __restrict__ aggx,
                                             const u16* __restrict__ pwT,
                                             const float* __restrict__ proj_b,
                                             const float* __restrict__ ln_g,
                                             const float* __restrict__ ln_b,
                                             float* __restrict__ out) {
    __shared__ __align__(16) u16 As[128 * ROWP];
    __shared__ __align__(16) u16 Bs[64 * ROWP];
    int tid = threadIdx.x;
    int m0 = blockIdx.x * 128;
    int wv = tid >> 6, l = tid & 63, lr = l & 15, lg = l >> 4;
    union FR { uint4 q; bf16x8 v; };
    f32x4 acc[2][4];
#pragma unroll
    for (int fr = 0; fr < 2; ++fr)
#pragma unroll
        for (int fc = 0; fc < 4; ++fc) acc[fr][fc] = (f32x4){0.f, 0.f, 0.f, 0.f};

    for (int kt = 0; kt < 8; ++kt) {
        int kb = kt * 128;
        __syncthreads();
#pragma unroll
        for (int p = 0; p < 8; ++p) {
            int idx = tid + p * 256;
            int row = idx >> 4, fo = idx & 15;
            int gm = m0 + row;
            uint4 v = make_uint4(0u, 0u, 0u, 0u);
            if (gm < N_NODES) v = *(const uint4*)(aggx + (size_t)gm * KAGG + kb + fo * 8);
            *(uint4*)&As[row * ROWP + fo * 8] = v;
        }
#pragma unroll
        for (int p = 0; p < 4; ++p) {
            int idx = tid + p * 256;
            int col = idx >> 4, fo = idx & 15;
            *(uint4*)&Bs[col * ROWP + fo * 8] =
                *(const uint4*)(pwT + (size_t)col * KAGG + kb + fo * 8);
        }
        __syncthreads();
#pragma unroll
        for (int ks = 0; ks < 4; ++ks) {
            int k0 = ks * 32;
            FR a0, a1, b0, b1, b2, b3;
            a0.q = *(const uint4*)&As[(wv * 32 + 0  + lr) * ROWP + k0 + 8 * lg];
            a1.q = *(const uint4*)&As[(wv * 32 + 16 + lr) * ROWP + k0 + 8 * lg];
            b0.q = *(const uint4*)&Bs[(0  + lr) * ROWP + k0 + 8 * lg];
            b1.q = *(const uint4*)&Bs[(16 + lr) * ROWP + k0 + 8 * lg];
            b2.q = *(const uint4*)&Bs[(32 + lr) * ROWP + k0 + 8 * lg];
            b3.q = *(const uint4*)&Bs[(48 + lr) * ROWP + k0 + 8 * lg];
            acc[0][0] = __builtin_amdgcn_mfma_f32_16x16x32_bf16(a0.v, b0.v, acc[0][0], 0, 0, 0);
            acc[0][1] = __builtin_amdgcn_mfma_f32_16x16x32_bf16(a0.v, b1.v, acc[0][1], 0, 0, 0);
            acc[0][2] = __builtin_amdgcn_mfma_f32_16x16x32_bf16(a0.v, b2.v, acc[0][2], 0, 0, 0);
            acc[0][3] = __builtin_amdgcn_mfma_f32_16x16x32_bf16(a0.v, b3.v, acc[0][3], 0, 0, 0);
            acc[1][0] = __builtin_amdgcn_mfma_f32_16x16x32_bf16(a1.v, b0.v, acc[1][0], 0, 0, 0);
            acc[1][1] = __builtin_amdgcn_mfma_f32_16x16x32_bf16(a1.v, b1.v, acc[1][1], 0, 0, 0);
            acc[1][2] = __builtin_amdgcn_mfma_f32_16x16x32_bf16(a1.v, b2.v, acc[1][2], 0, 0, 0);
            acc[1][3] = __builtin_amdgcn_mfma_f32_16x16x32_bf16(a1.v, b3.v, acc[1][3], 0, 0, 0);
        }
    }
    float pb4[4], g4[4], b4[4];
#pragma unroll
    for (int fc = 0; fc < 4; ++fc) {
        pb4[fc] = proj_b[fc * 16 + lr];
        g4[fc]  = ln_g[fc * 16 + lr];
        b4[fc]  = ln_b[fc * 16 + lr];
    }
#pragma unroll
    for (int fr = 0; fr < 2; ++fr)
#pragma unroll
        for (int r = 0; r < 4; ++r) {
            int gm = m0 + wv * 32 + fr * 16 + 4 * lg + r;
            float v[4];
#pragma unroll
            for (int fc = 0; fc < 4; ++fc) v[fc] = acc[fr][fc][r] + pb4[fc];
            float s = v[0] + v[1] + v[2] + v[3];
            s += __shfl_xor(s, 1); s += __shfl_xor(s, 2);
            s += __shfl_xor(s, 4); s += __shfl_xor(s, 8);
            float mu = s * (1.f / 64.f);
            float q = 0.f;
#pragma unroll
            for (int fc = 0; fc < 4; ++fc) { v[fc] -= mu; q = fmaf(v[fc], v[fc], q); }
            q += __shfl_xor(q, 1); q += __shfl_xor(q, 2);
            q += __shfl_xor(q, 4); q += __shfl_xor(q, 8);
            float inv = rsqrtf(q * (1.f / 64.f) + 1e-5f);
            if (gm < N_NODES) {
#pragma unroll
                for (int fc = 0; fc < 4; ++fc)
                    out[(size_t)gm * NCLASS + fc * 16 + lr] = v[fc] * inv * g4[fc] + b4[fc];
            }
        }
}

extern "C" void kernel_launch(void* const* d_in, const int* in_sizes, int n_in,
                              void* d_out, int out_size, void* d_ws, size_t ws_size,
                              hipStream_t stream) {
    const float* x      = (const float*)d_in[0];
    const int*   ei     = (const int*)  d_in[1];
    const float* eww    = (const float*)d_in[2];
    const float* w1     = (const float*)d_in[3];
    const float* b1v    = (const float*)d_in[4];
    const float* w2     = (const float*)d_in[5];
    const float* b2v    = (const float*)d_in[6];
    const float* proj_w = (const float*)d_in[7];
    const float* proj_b = (const float*)d_in[8];
    const float* ln_g   = (const float*)d_in[9];
    const float* ln_b   = (const float*)d_in[10];
    float* out = (float*)d_out;

    char* ws = (char*)d_ws;
    size_t off = 0;
    auto alloc = [&](size_t bytes) -> void* {
        void* p = ws + off;
        off = (off + bytes + 255) & ~(size_t)255;
        return p;
    };
    u16*   aggx   = (u16*)  alloc((size_t)N_NODES * KAGG * 2);    // 102.4 MB
    u16*   nb     = (u16*)  alloc((size_t)N_NODES * NAB * 2);     // 6.4 MB
    u16*   xb     = (u16*)  alloc((size_t)N_NODES * NFEAT * 2);   // 12.8 MB
    u16*   WpT    = (u16*)  alloc((size_t)NAB * NFEAT * 2);       // 16 KB
    u16*   pwT    = (u16*)  alloc((size_t)NCLASS * KAGG * 2);     // 128 KB
    u16*   wbuf   = (u16*)  alloc((size_t)ET_EDGES * 8 * 2);      // 13.6 MB
    int*   srcb   = (int*)  alloc((size_t)ET_EDGES * 4);          // 3.4 MB
    float* denom  = (float*)alloc(NHEADS * 4);
    int*   deg    = (int*)  alloc((size_t)N_NODES * 4);
    int*   rowptr = (int*)  alloc((size_t)(N_NODES + 1) * 4);
    int*   cursor = (int*)  alloc((size_t)N_NODES * 4);
    int*   bsum   = (int*)  alloc(64 * 4);
    int*   boff   = (int*)  alloc(64 * 4);
    if (off > ws_size) return;

    hipMemsetAsync(deg, 0, (size_t)N_NODES * 4, stream);
    hipMemsetAsync(denom, 0, NHEADS * 4, stream);

    k_pack_w<<<(NAB * NFEAT + 255) / 256, 256, 0, stream>>>(w1, WpT);
    k_pack_pw<<<(NCLASS * KAGG + 255) / 256, 256, 0, stream>>>(proj_w, pwT);
    k_deg<<<(N_EDGES + 255) / 256, 256, 0, stream>>>(ei, deg);
    k_scan1<<<NBLK_SCAN, 1024, 0, stream>>>(deg, rowptr, bsum);
    k_scan2<<<1, 64, 0, stream>>>(bsum, boff, rowptr);
    k_scan3<<<(N_NODES + 255) / 256, 256, 0, stream>>>(rowptr, boff, cursor);

    k_gemm<<<(N_NODES + 127) / 128, 256, 0, stream>>>(x, WpT, b1v, nb, xb);

    k_edges<<<(EHALF + 255) / 256, 256, 0, stream>>>(nb, ei, eww, w2, b2v,
                                                     cursor, wbuf, srcb, denom);
    k_agg<<<(N_NODES + 3) / 4, 256, 0, stream>>>(xb, wbuf, srcb, rowptr, denom, aggx);
    k_out<<<(N_NODES + 127) / 128, 256, 0, stream>>>(aggx, pwT, proj_b, ln_g, ln_b, out);
}